// Round 8
// baseline (635.489 us; speedup 1.0000x reference)
//
#include <hip/hip_runtime.h>

#define NN 50000
#define NE 800000
#define DD 96
#define BN_EPS 1e-5
#define NB 196    // ceil(NN/256)
#define GGEMM 782 // gemm grid: ceil(3125 tiles / 4 waves)

typedef __attribute__((ext_vector_type(8))) short short8v;
typedef __attribute__((ext_vector_type(4))) float float4v;

__device__ inline float bf2f(unsigned u) { return __uint_as_float(u << 16); }
__device__ inline unsigned short f2bf(float f) {
  unsigned u = __float_as_uint(f);
  return (unsigned short)((u + 0x7FFF + ((u >> 16) & 1)) >> 16);
}
__device__ inline void unpack8(uint4 v, float* f) {
  f[0] = bf2f(v.x & 0xffff); f[1] = bf2f(v.x >> 16);
  f[2] = bf2f(v.y & 0xffff); f[3] = bf2f(v.y >> 16);
  f[4] = bf2f(v.z & 0xffff); f[5] = bf2f(v.z >> 16);
  f[6] = bf2f(v.w & 0xffff); f[7] = bf2f(v.w >> 16);
}
__device__ inline uint4 pack8(const float* f) {
  uint4 v;
  v.x = (unsigned)f2bf(f[0]) | ((unsigned)f2bf(f[1]) << 16);
  v.y = (unsigned)f2bf(f[2]) | ((unsigned)f2bf(f[3]) << 16);
  v.z = (unsigned)f2bf(f[4]) | ((unsigned)f2bf(f[5]) << 16);
  v.w = (unsigned)f2bf(f[6]) | ((unsigned)f2bf(f[7]) << 16);
  return v;
}

// ============ fp32 -> bf16 convert ============
__global__ __launch_bounds__(256) void f2bf_k(const float* __restrict__ in,
                                              unsigned short* __restrict__ out,
                                              int n8) {
  int t = blockIdx.x * 256 + threadIdx.x;
  if (t >= n8) return;
  const float4* p = (const float4*)in + 2 * t;
  float4 a = p[0], b = p[1];
  float f[8] = {a.x, a.y, a.z, a.w, b.x, b.y, b.z, b.w};
  ((uint4*)out)[t] = pack8(f);
}

// ============ CSR build: histogram + per-edge rank in one pass ============
__global__ __launch_bounds__(256) void hist_rank(const int* __restrict__ dst,
                                                 int* __restrict__ counts,
                                                 int* __restrict__ rank) {
  int e = blockIdx.x * 256 + threadIdx.x;
  if (e < NE) rank[e] = atomicAdd(&counts[dst[e]], 1);
}

__global__ __launch_bounds__(256) void scan_part(const int* __restrict__ counts,
                                                 int* __restrict__ bsum) {
  __shared__ int s[256];
  int tid = threadIdx.x;
  int i = blockIdx.x * 256 + tid;
  s[tid] = (i < NN) ? counts[i] : 0;
  __syncthreads();
  for (int st = 128; st > 0; st >>= 1) {
    if (tid < st) s[tid] += s[tid + st];
    __syncthreads();
  }
  if (tid == 0) bsum[blockIdx.x] = s[0];
}

__global__ __launch_bounds__(256) void scan_top(const int* __restrict__ bsum,
                                                int* __restrict__ boff) {
  __shared__ int s[256];
  int tid = threadIdx.x;
  int v = (tid < NB) ? bsum[tid] : 0;
  s[tid] = v;
  __syncthreads();
  for (int off = 1; off < 256; off <<= 1) {
    int t = (tid >= off) ? s[tid - off] : 0;
    __syncthreads();
    s[tid] += t;
    __syncthreads();
  }
  if (tid < NB) boff[tid] = s[tid] - v;
}

__global__ __launch_bounds__(256) void scan_apply(
    const int* __restrict__ counts, const int* __restrict__ boff,
    int* __restrict__ rowstart) {
  __shared__ int s[256];
  int tid = threadIdx.x;
  int i = blockIdx.x * 256 + tid;
  int v = (i < NN) ? counts[i] : 0;
  s[tid] = v;
  __syncthreads();
  for (int off = 1; off < 256; off <<= 1) {
    int t = (tid >= off) ? s[tid - off] : 0;
    __syncthreads();
    s[tid] += t;
    __syncthreads();
  }
  if (i < NN) rowstart[i] = boff[blockIdx.x] + s[tid] - v;
  if (i == 0) rowstart[NN] = NE;
}

// pack entry: low 16 = src node (NN<65536), high 16 = ea as bf16
__global__ __launch_bounds__(256) void scatter_k(
    const int* __restrict__ src, const int* __restrict__ dst,
    const float* __restrict__ ea, const int* __restrict__ rowstart,
    const int* __restrict__ rank, unsigned* __restrict__ pack) {
  int e = blockIdx.x * 256 + threadIdx.x;
  if (e >= NE) return;
  int p = rowstart[dst[e]] + rank[e];
  pack[p] = (unsigned)src[e] | ((unsigned)f2bf(ea[e]) << 16);
}

// ===== wave-per-node CSR aggregation: lane = (c8, es), 2x5 edges in flight ===
__global__ __launch_bounds__(256) void agg_wave(
    const unsigned short* __restrict__ xin, const float* __restrict__ lw,
    const float* __restrict__ lb, const int* __restrict__ rowstart,
    const unsigned* __restrict__ pack, unsigned short* __restrict__ out) {
  int n = blockIdx.x * 4 + (threadIdx.x >> 6);  // grid exactly NN/4
  int lane = threadIdx.x & 63;
  int es = lane / 12;       // 0..5 (es==5 idle)
  int c8 = lane - es * 12;  // 0..11
  float lwv[8], lbv[8], acc[8];
#pragma unroll
  for (int i = 0; i < 8; i++) {
    lwv[i] = lw[c8 * 8 + i];
    lbv[i] = lb[c8 * 8 + i];
    acc[i] = 0.f;
  }
  if (es == 0) {
    uint4 xo = *(const uint4*)(xin + (size_t)n * DD + c8 * 8);
    unpack8(xo, acc);
  }
  int beg = rowstart[n], end = rowstart[n + 1];
  if (lane < 60) {
    int i = beg + es;
    for (; i + 5 < end; i += 10) {
      unsigned pk0 = pack[i], pk1 = pack[i + 5];
      float ev0 = bf2f(pk0 >> 16), ev1 = bf2f(pk1 >> 16);
      uint4 xv0 = *(const uint4*)(xin + (size_t)(pk0 & 0xffff) * DD + c8 * 8);
      uint4 xv1 = *(const uint4*)(xin + (size_t)(pk1 & 0xffff) * DD + c8 * 8);
      float xs0[8], xs1[8];
      unpack8(xv0, xs0);
      unpack8(xv1, xs1);
#pragma unroll
      for (int j = 0; j < 8; j++) {
        acc[j] += fmaxf(xs0[j] + fmaf(ev0, lwv[j], lbv[j]), 0.0f);
        acc[j] += fmaxf(xs1[j] + fmaf(ev1, lwv[j], lbv[j]), 0.0f);
      }
    }
    if (i < end) {
      unsigned pk = pack[i];
      float ev = bf2f(pk >> 16);
      uint4 xv = *(const uint4*)(xin + (size_t)(pk & 0xffff) * DD + c8 * 8);
      float xs[8];
      unpack8(xv, xs);
#pragma unroll
      for (int j = 0; j < 8; j++)
        acc[j] += fmaxf(xs[j] + fmaf(ev, lwv[j], lbv[j]), 0.0f);
    }
  }
#pragma unroll
  for (int j = 0; j < 8; j++) {
    float a = acc[j];
    float t1 = __shfl_down(a, 12);
    float t2 = __shfl_down(a, 24);
    float t3 = __shfl_down(a, 36);
    float t4 = __shfl_down(a, 48);
    acc[j] = a + t1 + t2 + t3 + t4;
  }
  if (es == 0)
    *(uint4*)(out + (size_t)n * DD + c8 * 8) = pack8(acc);
}

// ===== same, with BN affine (precomputed coeff) applied on the fly =====
__global__ __launch_bounds__(256) void agg_wave_norm(
    const unsigned short* __restrict__ h, const float* __restrict__ coeff,
    const float* __restrict__ lw, const float* __restrict__ lb,
    const int* __restrict__ rowstart, const unsigned* __restrict__ pack,
    unsigned short* __restrict__ out) {
  int n = blockIdx.x * 4 + (threadIdx.x >> 6);
  int lane = threadIdx.x & 63;
  int es = lane / 12;
  int c8 = lane - es * 12;
  float sc[8], tsh[8], tlb[8], lwv[8], acc[8];
#pragma unroll
  for (int i = 0; i < 8; i++) {
    sc[i] = coeff[c8 * 8 + i];
    tsh[i] = coeff[96 + c8 * 8 + i];
    tlb[i] = tsh[i] + lb[c8 * 8 + i];
    lwv[i] = lw[c8 * 8 + i];
    acc[i] = 0.f;
  }
  if (es == 0) {
    uint4 xo = *(const uint4*)(h + (size_t)n * DD + c8 * 8);
    float f[8];
    unpack8(xo, f);
#pragma unroll
    for (int i = 0; i < 8; i++) acc[i] = fmaf(sc[i], f[i], tsh[i]);
  }
  int beg = rowstart[n], end = rowstart[n + 1];
  if (lane < 60) {
    int i = beg + es;
    for (; i + 5 < end; i += 10) {
      unsigned pk0 = pack[i], pk1 = pack[i + 5];
      float ev0 = bf2f(pk0 >> 16), ev1 = bf2f(pk1 >> 16);
      uint4 xv0 = *(const uint4*)(h + (size_t)(pk0 & 0xffff) * DD + c8 * 8);
      uint4 xv1 = *(const uint4*)(h + (size_t)(pk1 & 0xffff) * DD + c8 * 8);
      float xs0[8], xs1[8];
      unpack8(xv0, xs0);
      unpack8(xv1, xs1);
#pragma unroll
      for (int j = 0; j < 8; j++) {
        acc[j] += fmaxf(fmaf(sc[j], xs0[j], fmaf(ev0, lwv[j], tlb[j])), 0.0f);
        acc[j] += fmaxf(fmaf(sc[j], xs1[j], fmaf(ev1, lwv[j], tlb[j])), 0.0f);
      }
    }
    if (i < end) {
      unsigned pk = pack[i];
      float ev = bf2f(pk >> 16);
      uint4 xv = *(const uint4*)(h + (size_t)(pk & 0xffff) * DD + c8 * 8);
      float xs[8];
      unpack8(xv, xs);
#pragma unroll
      for (int j = 0; j < 8; j++)
        acc[j] += fmaxf(fmaf(sc[j], xs[j], fmaf(ev, lwv[j], tlb[j])), 0.0f);
    }
  }
#pragma unroll
  for (int j = 0; j < 8; j++) {
    float a = acc[j];
    float t1 = __shfl_down(a, 12);
    float t2 = __shfl_down(a, 24);
    float t3 = __shfl_down(a, 36);
    float t4 = __shfl_down(a, 48);
    acc[j] = a + t1 + t2 + t3 + t4;
  }
  if (es == 0)
    *(uint4*)(out + (size_t)n * DD + c8 * 8) = pack8(acc);
}

// ============ W prep: fold BN scales (two coeff regions), bf16, swizzle =====
// cA layout: scale[0..KA), shift[KA..2KA); cB: scale[0..KB), shift[KB..2KB)
template <int K, int M, int KA, int KB>
__global__ __launch_bounds__(256) void wprep(const float* __restrict__ W,
                                             const float* __restrict__ b,
                                             const float* __restrict__ cA,
                                             const float* __restrict__ cB,
                                             unsigned short* __restrict__ Wz,
                                             float* __restrict__ bf) {
  constexpr int KT = K / 32, MT = M / 16;
  int t = blockIdx.x * 256 + threadIdx.x;
  if (t < KT * MT * 64) {
    int lane = t & 63, fr = t >> 6;
    int kt = fr / MT, ct = fr - kt * MT;
    int col = ct * 16 + (lane & 15);
    int k0 = kt * 32 + (lane >> 4) * 8;
    float f[8];
#pragma unroll
    for (int j = 0; j < 8; j++) {
      int k = k0 + j;
      float w = W[k * M + col];
      if (KA > 0 && k < KA) w *= cA[k];
      if (KB > 0 && k >= KA && k < KA + KB) w *= cB[k - KA];
      f[j] = w;
    }
    ((uint4*)Wz)[t] = pack8(f);
  } else if (t < KT * MT * 64 + M) {
    int j = t - KT * MT * 64;
    float acc = b[j];
    if (KA > 0)
      for (int k = 0; k < KA; k++) acc += cA[KA + k] * W[k * M + j];
    if (KB > 0)
      for (int k = 0; k < KB; k++) acc += cB[KB + k] * W[(KA + k) * M + j];
    bf[j] = acc;
  }
}

// ============ MFMA GEMM + bias + relu + per-block column stats ============
// stats: per-block fp32 partials (no atomics): partial[blk][0..M)=sum,
// partial[blk][M..2M)=sumsq
template <int K1, int K2, int M, bool OUTF32>
__global__ __launch_bounds__(256) void gemm_mfma(
    const unsigned short* __restrict__ A1,
    const unsigned short* __restrict__ A2,
    const unsigned short* __restrict__ Wz, const float* __restrict__ bias,
    void* __restrict__ hOut, float* __restrict__ partial) {
  constexpr int K = K1 + K2;
  constexpr int KT = K / 32;
  constexpr int MT = M / 16;
  constexpr int NT = NN / 16;  // 3125
  int tid = threadIdx.x;
  int wave = tid >> 6, lane = tid & 63;
  int lr = lane & 15, lk = lane >> 4;

  float bj[MT], s[MT], q[MT];
#pragma unroll
  for (int ct = 0; ct < MT; ct++) {
    bj[ct] = bias[ct * 16 + lr];
    s[ct] = 0.f;
    q[ct] = 0.f;
  }

  for (int tt = blockIdx.x * 4 + wave; tt < NT; tt += gridDim.x * 4) {
    float4v acc[MT];
#pragma unroll
    for (int ct = 0; ct < MT; ct++) acc[ct] = (float4v){0.f, 0.f, 0.f, 0.f};

    const unsigned short* a1 = A1 + (size_t)(tt * 16 + lr) * K1 + lk * 8;
    const unsigned short* a2 =
        (K2 > 0) ? A2 + (size_t)(tt * 16 + lr) * K2 + lk * 8 : a1;
#pragma unroll
    for (int kt = 0; kt < KT; kt++) {
      short8v av;
      if (kt * 32 < K1)
        av = *reinterpret_cast<const short8v*>(a1 + kt * 32);
      else
        av = *reinterpret_cast<const short8v*>(a2 + (kt * 32 - K1));
#pragma unroll
      for (int ct = 0; ct < MT; ct++) {
        short8v bv = *reinterpret_cast<const short8v*>(
            Wz + ((size_t)(kt * MT + ct) * 64 + lane) * 8);
        acc[ct] =
            __builtin_amdgcn_mfma_f32_16x16x32_bf16(av, bv, acc[ct], 0, 0, 0);
      }
    }
#pragma unroll
    for (int ct = 0; ct < MT; ct++) {
#pragma unroll
      for (int i = 0; i < 4; i++) {
        float o = fmaxf(acc[ct][i] + bj[ct], 0.f);
        size_t row = (size_t)tt * 16 + lk * 4 + i;
        if (OUTF32)
          ((float*)hOut)[row * M + ct * 16 + lr] = o;
        else
          ((unsigned short*)hOut)[row * M + ct * 16 + lr] = f2bf(o);
        s[ct] += o;
        q[ct] += o * o;
      }
    }
  }

  __shared__ float sred[4][M], qred[4][M];
#pragma unroll
  for (int ct = 0; ct < MT; ct++) {
    float ss = s[ct], qq = q[ct];
    ss += __shfl_xor(ss, 16);
    ss += __shfl_xor(ss, 32);
    qq += __shfl_xor(qq, 16);
    qq += __shfl_xor(qq, 32);
    if (lk == 0) {
      sred[wave][ct * 16 + lr] = ss;
      qred[wave][ct * 16 + lr] = qq;
    }
  }
  __syncthreads();
  if (tid < M) {
    partial[(size_t)blockIdx.x * (2 * M) + tid] =
        sred[0][tid] + sred[1][tid] + sred[2][tid] + sred[3][tid];
  } else if (tid < 2 * M) {
    int j = tid - M;
    partial[(size_t)blockIdx.x * (2 * M) + tid] =
        qred[0][j] + qred[1][j] + qred[2][j] + qred[3][j];
  }
}

// ============ reduce per-block partials -> BN coeff (scale/shift) ==========
template <int M>
__global__ __launch_bounds__(256) void bn_red(const float* __restrict__ partial,
                                              const float* __restrict__ g,
                                              const float* __restrict__ beta,
                                              float* __restrict__ coeff) {
  __shared__ double dsum[2 * M];
  int tid = threadIdx.x;
  if (tid < 2 * M) {
    double a = 0.0;
    for (int b = 0; b < GGEMM; b++) a += partial[(size_t)b * (2 * M) + tid];
    dsum[tid] = a;
  }
  __syncthreads();
  if (tid < M) {
    double mu = dsum[tid] / (double)NN;
    double var = dsum[M + tid] / (double)NN - mu * mu;
    double inv = 1.0 / sqrt(var + (double)BN_EPS);
    double sc = (double)g[tid] * inv;
    coeff[tid] = (float)sc;
    coeff[M + tid] = (float)((double)beta[tid] - mu * sc);
  }
}

// ============ final normalize from coeff, M=16, fp32 ============
__global__ __launch_bounds__(256) void bnout(const float4* __restrict__ h,
                                             const float* __restrict__ coeff,
                                             float4* __restrict__ out) {
  int t = blockIdx.x * 256 + threadIdx.x;
  if (t >= NN * 4) return;
  float4 v = h[t];
  int j0 = (4 * t) & 15;
  float4 o;
  o.x = fmaf(v.x, coeff[j0 + 0], coeff[16 + j0 + 0]);
  o.y = fmaf(v.y, coeff[j0 + 1], coeff[16 + j0 + 1]);
  o.z = fmaf(v.z, coeff[j0 + 2], coeff[16 + j0 + 2]);
  o.w = fmaf(v.w, coeff[j0 + 3], coeff[16 + j0 + 3]);
  out[t] = o;
}

static inline char* alignup(char* p, size_t a) {
  return (char*)(((uintptr_t)p + a - 1) & ~(uintptr_t)(a - 1));
}

extern "C" void kernel_launch(void* const* d_in, const int* in_sizes, int n_in,
                              void* d_out, int out_size, void* d_ws,
                              size_t ws_size, hipStream_t stream) {
  const float* x = (const float*)d_in[0];
  const float* ea = (const float*)d_in[1];
  const int* ei = (const int*)d_in[2];
  const int* src = ei;
  const int* dst = ei + NE;
  const float* lin_w = (const float*)d_in[3];
  const float* lin_b = (const float*)d_in[4];
  const float* c1_w = (const float*)d_in[5];
  const float* c1_b = (const float*)d_in[6];
  const float* c1_g = (const float*)d_in[7];
  const float* c1_be = (const float*)d_in[8];
  const float* c2_w = (const float*)d_in[9];
  const float* c2_b = (const float*)d_in[10];
  const float* c2_g = (const float*)d_in[11];
  const float* c2_be = (const float*)d_in[12];
  const float* l1_w = (const float*)d_in[13];
  const float* l1_b = (const float*)d_in[14];
  const float* l1_g = (const float*)d_in[15];
  const float* l1_be = (const float*)d_in[16];
  const float* ma_w = (const float*)d_in[17];
  const float* ma_b = (const float*)d_in[18];
  const float* ma_g = (const float*)d_in[19];
  const float* ma_be = (const float*)d_in[20];
  const float* mb_w = (const float*)d_in[21];
  const float* mb_b = (const float*)d_in[22];
  const float* mb_g = (const float*)d_in[23];
  const float* mb_be = (const float*)d_in[24];

  typedef unsigned short us;
  char* p = (char*)d_ws;
  us* xb = (us*)p;   p += (size_t)NN * 96 * 2;
  us* Ab = (us*)p;   p += (size_t)NN * 96 * 2;
  us* H1 = (us*)p;   p += (size_t)NN * 96 * 2;
  us* H2 = (us*)p;   p += (size_t)NN * 64 * 2;
  us* H3 = (us*)p;   p += (size_t)NN * 96 * 2;
  us* H4 = (us*)p;   p += (size_t)NN * 96 * 2;
  float* H5 = (float*)p; p += (size_t)NN * 16 * 4;
  p = alignup(p, 256);
  us* Wz1 = (us*)p;  p += 3 * 6 * 64 * 8 * 2;
  us* Wz2 = (us*)p;  p += 3 * 4 * 64 * 8 * 2;
  us* Wz3 = (us*)p;  p += 5 * 6 * 64 * 8 * 2;
  us* Wz4 = (us*)p;  p += 3 * 6 * 64 * 8 * 2;
  us* Wz5 = (us*)p;  p += 3 * 1 * 64 * 8 * 2;
  p = alignup(p, 256);
  float* bf1 = (float*)p; p += 96 * 4;
  float* bf2 = (float*)p; p += 64 * 4;
  float* bf3 = (float*)p; p += 96 * 4;
  float* bf4 = (float*)p; p += 96 * 4;
  float* bf5 = (float*)p; p += 16 * 4;
  float* co1 = (float*)p; p += 192 * 4;
  float* co2 = (float*)p; p += 128 * 4;
  float* co3 = (float*)p; p += 192 * 4;
  float* co4 = (float*)p; p += 192 * 4;
  float* co5 = (float*)p; p += 32 * 4;
  p = alignup(p, 256);
  float* partial = (float*)p; p += (size_t)GGEMM * 192 * 4;
  p = alignup(p, 256);
  char* zbase = p;
  int* counts = (int*)p;  p += (size_t)NN * 4;
  size_t zbytes = (size_t)(p - zbase);
  int* rowstart = (int*)p; p += (size_t)(NN + 1) * 4;
  int* bsum = (int*)p;    p += 256 * 4;
  int* boff = (int*)p;    p += 256 * 4;
  int* rank = (int*)p;    p += (size_t)NE * 4;
  unsigned* pack = (unsigned*)p; p += (size_t)NE * 4;

  hipMemsetAsync(zbase, 0, zbytes, stream);

  const int eb = (NE + 255) / 256;
  const int n12 = NN * 12;
  const int b12 = (n12 + 255) / 256;
  const int aggG = NN / 4;  // 12500, exact

  // ---- prep ----
  f2bf_k<<<b12, 256, 0, stream>>>(x, xb, n12);
  hist_rank<<<eb, 256, 0, stream>>>(dst, counts, rank);
  scan_part<<<NB, 256, 0, stream>>>(counts, bsum);
  scan_top<<<1, 256, 0, stream>>>(bsum, boff);
  scan_apply<<<NB, 256, 0, stream>>>(counts, boff, rowstart);
  scatter_k<<<eb, 256, 0, stream>>>(src, dst, ea, rowstart, rank, pack);

  // ---- conv1 ----
  agg_wave<<<aggG, 256, 0, stream>>>(xb, lin_w, lin_b, rowstart, pack, Ab);
  wprep<96, 96, 0, 0><<<5, 256, 0, stream>>>(c1_w, c1_b, nullptr, nullptr, Wz1,
                                             bf1);
  gemm_mfma<96, 0, 96, false><<<GGEMM, 256, 0, stream>>>(Ab, nullptr, Wz1, bf1,
                                                         H1, partial);
  bn_red<96><<<1, 256, 0, stream>>>(partial, c1_g, c1_be, co1);

  // ---- conv2 (BN1 coeff applied on the fly to H1) ----
  agg_wave_norm<<<aggG, 256, 0, stream>>>(H1, co1, lin_w, lin_b, rowstart,
                                          pack, Ab);
  wprep<96, 64, 0, 0><<<4, 256, 0, stream>>>(c2_w, c2_b, nullptr, nullptr, Wz2,
                                             bf2);
  gemm_mfma<96, 0, 64, false><<<GGEMM, 256, 0, stream>>>(Ab, nullptr, Wz2, bf2,
                                                         H2, partial);
  bn_red<64><<<1, 256, 0, stream>>>(partial, c2_g, c2_be, co2);

  // ---- lin1 on concat([H1(BN1 folded), H2(BN2 folded)]) ----
  wprep<160, 96, 96, 64><<<8, 256, 0, stream>>>(l1_w, l1_b, co1, co2, Wz3,
                                                bf3);
  gemm_mfma<96, 64, 96, false><<<GGEMM, 256, 0, stream>>>(H1, H2, Wz3, bf3, H3,
                                                          partial);
  bn_red<96><<<1, 256, 0, stream>>>(partial, l1_g, l1_be, co3);

  // ---- mlp1a (BN3 folded) ----
  wprep<96, 96, 96, 0><<<5, 256, 0, stream>>>(ma_w, ma_b, co3, nullptr, Wz4,
                                              bf4);
  gemm_mfma<96, 0, 96, false><<<GGEMM, 256, 0, stream>>>(H3, nullptr, Wz4, bf4,
                                                         H4, partial);
  bn_red<96><<<1, 256, 0, stream>>>(partial, ma_g, ma_be, co4);

  // ---- mlp1b (BN4 folded) -> H5 fp32, then BN5 via bn_red + bnout ----
  wprep<96, 16, 96, 0><<<1, 256, 0, stream>>>(mb_w, mb_b, co4, nullptr, Wz5,
                                              bf5);
  gemm_mfma<96, 0, 16, true><<<GGEMM, 256, 0, stream>>>(H4, nullptr, Wz5, bf5,
                                                        H5, partial);
  bn_red<16><<<1, 256, 0, stream>>>(partial, mb_g, mb_be, co5);
  bnout<<<(NN * 4 + 255) / 256, 256, 0, stream>>>((const float4*)H5, co5,
                                                  (float4*)d_out);
}

// Round 9
// 322.961 us; speedup vs baseline: 1.9677x; 1.9677x over previous
//
#include <hip/hip_runtime.h>

#define NN 50000
#define NE 800000
#define DD 96
#define BN_EPS 1e-5
#define NB 196    // ceil(NN/256)
#define GGEMM 782 // gemm grid: ceil(3125 tiles / 4 waves)

typedef __attribute__((ext_vector_type(8))) short short8v;
typedef __attribute__((ext_vector_type(4))) float float4v;

__device__ inline float bf2f(unsigned u) { return __uint_as_float(u << 16); }
__device__ inline unsigned short f2bf(float f) {
  unsigned u = __float_as_uint(f);
  return (unsigned short)((u + 0x7FFF + ((u >> 16) & 1)) >> 16);
}
__device__ inline void unpack8(uint4 v, float* f) {
  f[0] = bf2f(v.x & 0xffff); f[1] = bf2f(v.x >> 16);
  f[2] = bf2f(v.y & 0xffff); f[3] = bf2f(v.y >> 16);
  f[4] = bf2f(v.z & 0xffff); f[5] = bf2f(v.z >> 16);
  f[6] = bf2f(v.w & 0xffff); f[7] = bf2f(v.w >> 16);
}
__device__ inline uint4 pack8(const float* f) {
  uint4 v;
  v.x = (unsigned)f2bf(f[0]) | ((unsigned)f2bf(f[1]) << 16);
  v.y = (unsigned)f2bf(f[2]) | ((unsigned)f2bf(f[3]) << 16);
  v.z = (unsigned)f2bf(f[4]) | ((unsigned)f2bf(f[5]) << 16);
  v.w = (unsigned)f2bf(f[6]) | ((unsigned)f2bf(f[7]) << 16);
  return v;
}

// ============ fp32 -> bf16 convert ============
__global__ __launch_bounds__(256) void f2bf_k(const float* __restrict__ in,
                                              unsigned short* __restrict__ out,
                                              int n8) {
  int t = blockIdx.x * 256 + threadIdx.x;
  if (t >= n8) return;
  const float4* p = (const float4*)in + 2 * t;
  float4 a = p[0], b = p[1];
  float f[8] = {a.x, a.y, a.z, a.w, b.x, b.y, b.z, b.w};
  ((uint4*)out)[t] = pack8(f);
}

// ============ CSR build: histogram + per-edge rank in one pass ============
__global__ __launch_bounds__(256) void hist_rank(const int* __restrict__ dst,
                                                 int* __restrict__ counts,
                                                 int* __restrict__ rank) {
  int e = blockIdx.x * 256 + threadIdx.x;
  if (e < NE) rank[e] = atomicAdd(&counts[dst[e]], 1);
}

__global__ __launch_bounds__(256) void scan_part(const int* __restrict__ counts,
                                                 int* __restrict__ bsum) {
  __shared__ int s[256];
  int tid = threadIdx.x;
  int i = blockIdx.x * 256 + tid;
  s[tid] = (i < NN) ? counts[i] : 0;
  __syncthreads();
  for (int st = 128; st > 0; st >>= 1) {
    if (tid < st) s[tid] += s[tid + st];
    __syncthreads();
  }
  if (tid == 0) bsum[blockIdx.x] = s[0];
}

__global__ __launch_bounds__(256) void scan_top(const int* __restrict__ bsum,
                                                int* __restrict__ boff) {
  __shared__ int s[256];
  int tid = threadIdx.x;
  int v = (tid < NB) ? bsum[tid] : 0;
  s[tid] = v;
  __syncthreads();
  for (int off = 1; off < 256; off <<= 1) {
    int t = (tid >= off) ? s[tid - off] : 0;
    __syncthreads();
    s[tid] += t;
    __syncthreads();
  }
  if (tid < NB) boff[tid] = s[tid] - v;
}

__global__ __launch_bounds__(256) void scan_apply(
    const int* __restrict__ counts, const int* __restrict__ boff,
    int* __restrict__ rowstart) {
  __shared__ int s[256];
  int tid = threadIdx.x;
  int i = blockIdx.x * 256 + tid;
  int v = (i < NN) ? counts[i] : 0;
  s[tid] = v;
  __syncthreads();
  for (int off = 1; off < 256; off <<= 1) {
    int t = (tid >= off) ? s[tid - off] : 0;
    __syncthreads();
    s[tid] += t;
    __syncthreads();
  }
  if (i < NN) rowstart[i] = boff[blockIdx.x] + s[tid] - v;
  if (i == 0) rowstart[NN] = NE;
}

// pack entry: low 16 = src node (NN<65536), high 16 = ea as bf16
__global__ __launch_bounds__(256) void scatter_k(
    const int* __restrict__ src, const int* __restrict__ dst,
    const float* __restrict__ ea, const int* __restrict__ rowstart,
    const int* __restrict__ rank, unsigned* __restrict__ pack) {
  int e = blockIdx.x * 256 + threadIdx.x;
  if (e >= NE) return;
  int p = rowstart[dst[e]] + rank[e];
  pack[p] = (unsigned)src[e] | ((unsigned)f2bf(ea[e]) << 16);
}

// ===== wave-per-node CSR aggregation: lane = (c8, es), 2x5 edges in flight ===
__global__ __launch_bounds__(256) void agg_wave(
    const unsigned short* __restrict__ xin, const float* __restrict__ lw,
    const float* __restrict__ lb, const int* __restrict__ rowstart,
    const unsigned* __restrict__ pack, unsigned short* __restrict__ out) {
  int n = blockIdx.x * 4 + (threadIdx.x >> 6);  // grid exactly NN/4
  int lane = threadIdx.x & 63;
  int es = lane / 12;       // 0..5 (es==5 idle)
  int c8 = lane - es * 12;  // 0..11
  float lwv[8], lbv[8], acc[8];
#pragma unroll
  for (int i = 0; i < 8; i++) {
    lwv[i] = lw[c8 * 8 + i];
    lbv[i] = lb[c8 * 8 + i];
    acc[i] = 0.f;
  }
  if (es == 0) {
    uint4 xo = *(const uint4*)(xin + (size_t)n * DD + c8 * 8);
    unpack8(xo, acc);
  }
  int beg = rowstart[n], end = rowstart[n + 1];
  if (lane < 60) {
    int i = beg + es;
    for (; i + 5 < end; i += 10) {
      unsigned pk0 = pack[i], pk1 = pack[i + 5];
      float ev0 = bf2f(pk0 >> 16), ev1 = bf2f(pk1 >> 16);
      uint4 xv0 = *(const uint4*)(xin + (size_t)(pk0 & 0xffff) * DD + c8 * 8);
      uint4 xv1 = *(const uint4*)(xin + (size_t)(pk1 & 0xffff) * DD + c8 * 8);
      float xs0[8], xs1[8];
      unpack8(xv0, xs0);
      unpack8(xv1, xs1);
#pragma unroll
      for (int j = 0; j < 8; j++) {
        acc[j] += fmaxf(xs0[j] + fmaf(ev0, lwv[j], lbv[j]), 0.0f);
        acc[j] += fmaxf(xs1[j] + fmaf(ev1, lwv[j], lbv[j]), 0.0f);
      }
    }
    if (i < end) {
      unsigned pk = pack[i];
      float ev = bf2f(pk >> 16);
      uint4 xv = *(const uint4*)(xin + (size_t)(pk & 0xffff) * DD + c8 * 8);
      float xs[8];
      unpack8(xv, xs);
#pragma unroll
      for (int j = 0; j < 8; j++)
        acc[j] += fmaxf(xs[j] + fmaf(ev, lwv[j], lbv[j]), 0.0f);
    }
  }
#pragma unroll
  for (int j = 0; j < 8; j++) {
    float a = acc[j];
    float t1 = __shfl_down(a, 12);
    float t2 = __shfl_down(a, 24);
    float t3 = __shfl_down(a, 36);
    float t4 = __shfl_down(a, 48);
    acc[j] = a + t1 + t2 + t3 + t4;
  }
  if (es == 0)
    *(uint4*)(out + (size_t)n * DD + c8 * 8) = pack8(acc);
}

// ===== same, with BN affine (precomputed coeff) applied on the fly =====
__global__ __launch_bounds__(256) void agg_wave_norm(
    const unsigned short* __restrict__ h, const float* __restrict__ coeff,
    const float* __restrict__ lw, const float* __restrict__ lb,
    const int* __restrict__ rowstart, const unsigned* __restrict__ pack,
    unsigned short* __restrict__ out) {
  int n = blockIdx.x * 4 + (threadIdx.x >> 6);
  int lane = threadIdx.x & 63;
  int es = lane / 12;
  int c8 = lane - es * 12;
  float sc[8], tsh[8], tlb[8], lwv[8], acc[8];
#pragma unroll
  for (int i = 0; i < 8; i++) {
    sc[i] = coeff[c8 * 8 + i];
    tsh[i] = coeff[96 + c8 * 8 + i];
    tlb[i] = tsh[i] + lb[c8 * 8 + i];
    lwv[i] = lw[c8 * 8 + i];
    acc[i] = 0.f;
  }
  if (es == 0) {
    uint4 xo = *(const uint4*)(h + (size_t)n * DD + c8 * 8);
    float f[8];
    unpack8(xo, f);
#pragma unroll
    for (int i = 0; i < 8; i++) acc[i] = fmaf(sc[i], f[i], tsh[i]);
  }
  int beg = rowstart[n], end = rowstart[n + 1];
  if (lane < 60) {
    int i = beg + es;
    for (; i + 5 < end; i += 10) {
      unsigned pk0 = pack[i], pk1 = pack[i + 5];
      float ev0 = bf2f(pk0 >> 16), ev1 = bf2f(pk1 >> 16);
      uint4 xv0 = *(const uint4*)(h + (size_t)(pk0 & 0xffff) * DD + c8 * 8);
      uint4 xv1 = *(const uint4*)(h + (size_t)(pk1 & 0xffff) * DD + c8 * 8);
      float xs0[8], xs1[8];
      unpack8(xv0, xs0);
      unpack8(xv1, xs1);
#pragma unroll
      for (int j = 0; j < 8; j++) {
        acc[j] += fmaxf(fmaf(sc[j], xs0[j], fmaf(ev0, lwv[j], tlb[j])), 0.0f);
        acc[j] += fmaxf(fmaf(sc[j], xs1[j], fmaf(ev1, lwv[j], tlb[j])), 0.0f);
      }
    }
    if (i < end) {
      unsigned pk = pack[i];
      float ev = bf2f(pk >> 16);
      uint4 xv = *(const uint4*)(h + (size_t)(pk & 0xffff) * DD + c8 * 8);
      float xs[8];
      unpack8(xv, xs);
#pragma unroll
      for (int j = 0; j < 8; j++)
        acc[j] += fmaxf(fmaf(sc[j], xs[j], fmaf(ev, lwv[j], tlb[j])), 0.0f);
    }
  }
#pragma unroll
  for (int j = 0; j < 8; j++) {
    float a = acc[j];
    float t1 = __shfl_down(a, 12);
    float t2 = __shfl_down(a, 24);
    float t3 = __shfl_down(a, 36);
    float t4 = __shfl_down(a, 48);
    acc[j] = a + t1 + t2 + t3 + t4;
  }
  if (es == 0)
    *(uint4*)(out + (size_t)n * DD + c8 * 8) = pack8(acc);
}

// ============ W prep: fold BN scales (two coeff regions), bf16, swizzle =====
// cA layout: scale[0..KA), shift[KA..2KA); cB: scale[0..KB), shift[KB..2KB)
template <int K, int M, int KA, int KB>
__global__ __launch_bounds__(256) void wprep(const float* __restrict__ W,
                                             const float* __restrict__ b,
                                             const float* __restrict__ cA,
                                             const float* __restrict__ cB,
                                             unsigned short* __restrict__ Wz,
                                             float* __restrict__ bf) {
  constexpr int KT = K / 32, MT = M / 16;
  int t = blockIdx.x * 256 + threadIdx.x;
  if (t < KT * MT * 64) {
    int lane = t & 63, fr = t >> 6;
    int kt = fr / MT, ct = fr - kt * MT;
    int col = ct * 16 + (lane & 15);
    int k0 = kt * 32 + (lane >> 4) * 8;
    float f[8];
#pragma unroll
    for (int j = 0; j < 8; j++) {
      int k = k0 + j;
      float w = W[k * M + col];
      if (KA > 0 && k < KA) w *= cA[k];
      if (KB > 0 && k >= KA && k < KA + KB) w *= cB[k - KA];
      f[j] = w;
    }
    ((uint4*)Wz)[t] = pack8(f);
  } else if (t < KT * MT * 64 + M) {
    int j = t - KT * MT * 64;
    float acc = b[j];
    if (KA > 0)
      for (int k = 0; k < KA; k++) acc += cA[KA + k] * W[k * M + j];
    if (KB > 0)
      for (int k = 0; k < KB; k++) acc += cB[KB + k] * W[(KA + k) * M + j];
    bf[j] = acc;
  }
}

// ============ MFMA GEMM + bias + relu + per-block column stats ============
template <int K1, int K2, int M, bool OUTF32>
__global__ __launch_bounds__(256) void gemm_mfma(
    const unsigned short* __restrict__ A1,
    const unsigned short* __restrict__ A2,
    const unsigned short* __restrict__ Wz, const float* __restrict__ bias,
    void* __restrict__ hOut, float* __restrict__ partial) {
  constexpr int K = K1 + K2;
  constexpr int KT = K / 32;
  constexpr int MT = M / 16;
  constexpr int NT = NN / 16;  // 3125
  int tid = threadIdx.x;
  int wave = tid >> 6, lane = tid & 63;
  int lr = lane & 15, lk = lane >> 4;

  float bj[MT], s[MT], q[MT];
#pragma unroll
  for (int ct = 0; ct < MT; ct++) {
    bj[ct] = bias[ct * 16 + lr];
    s[ct] = 0.f;
    q[ct] = 0.f;
  }

  for (int tt = blockIdx.x * 4 + wave; tt < NT; tt += gridDim.x * 4) {
    float4v acc[MT];
#pragma unroll
    for (int ct = 0; ct < MT; ct++) acc[ct] = (float4v){0.f, 0.f, 0.f, 0.f};

    const unsigned short* a1 = A1 + (size_t)(tt * 16 + lr) * K1 + lk * 8;
    const unsigned short* a2 =
        (K2 > 0) ? A2 + (size_t)(tt * 16 + lr) * K2 + lk * 8 : a1;
#pragma unroll
    for (int kt = 0; kt < KT; kt++) {
      short8v av;
      if (kt * 32 < K1)
        av = *reinterpret_cast<const short8v*>(a1 + kt * 32);
      else
        av = *reinterpret_cast<const short8v*>(a2 + (kt * 32 - K1));
#pragma unroll
      for (int ct = 0; ct < MT; ct++) {
        short8v bv = *reinterpret_cast<const short8v*>(
            Wz + ((size_t)(kt * MT + ct) * 64 + lane) * 8);
        acc[ct] =
            __builtin_amdgcn_mfma_f32_16x16x32_bf16(av, bv, acc[ct], 0, 0, 0);
      }
    }
#pragma unroll
    for (int ct = 0; ct < MT; ct++) {
#pragma unroll
      for (int i = 0; i < 4; i++) {
        float o = fmaxf(acc[ct][i] + bj[ct], 0.f);
        size_t row = (size_t)tt * 16 + lk * 4 + i;
        if (OUTF32)
          ((float*)hOut)[row * M + ct * 16 + lr] = o;
        else
          ((unsigned short*)hOut)[row * M + ct * 16 + lr] = f2bf(o);
        s[ct] += o;
        q[ct] += o * o;
      }
    }
  }

  __shared__ float sred[4][M], qred[4][M];
#pragma unroll
  for (int ct = 0; ct < MT; ct++) {
    float ss = s[ct], qq = q[ct];
    ss += __shfl_xor(ss, 16);
    ss += __shfl_xor(ss, 32);
    qq += __shfl_xor(qq, 16);
    qq += __shfl_xor(qq, 32);
    if (lk == 0) {
      sred[wave][ct * 16 + lr] = ss;
      qred[wave][ct * 16 + lr] = qq;
    }
  }
  __syncthreads();
  if (tid < M) {
    partial[(size_t)blockIdx.x * (2 * M) + tid] =
        sred[0][tid] + sred[1][tid] + sred[2][tid] + sred[3][tid];
  } else if (tid < 2 * M) {
    int j = tid - M;
    partial[(size_t)blockIdx.x * (2 * M) + tid] =
        qred[0][j] + qred[1][j] + qred[2][j] + qred[3][j];
  }
}

// ==== reduce partials -> BN coeff: ONE BLOCK PER COLUMN (parallel) ====
// block col handles sum (col) and sumsq (col+M); thread t strides blocks.
template <int M>
__global__ __launch_bounds__(256) void bn_red(const float* __restrict__ partial,
                                              const float* __restrict__ g,
                                              const float* __restrict__ beta,
                                              float* __restrict__ coeff) {
  __shared__ double ls[256], lq[256];
  int col = blockIdx.x;  // 0..M-1
  int tid = threadIdx.x;
  double s = 0.0, q = 0.0;
  for (int b = tid; b < GGEMM; b += 256) {
    const float* row = partial + (size_t)b * (2 * M);
    s += row[col];
    q += row[M + col];
  }
  ls[tid] = s;
  lq[tid] = q;
  __syncthreads();
  for (int st = 128; st > 0; st >>= 1) {
    if (tid < st) {
      ls[tid] += ls[tid + st];
      lq[tid] += lq[tid + st];
    }
    __syncthreads();
  }
  if (tid == 0) {
    double mu = ls[0] / (double)NN;
    double var = lq[0] / (double)NN - mu * mu;
    double inv = 1.0 / sqrt(var + (double)BN_EPS);
    double sc = (double)g[col] * inv;
    coeff[col] = (float)sc;
    coeff[M + col] = (float)((double)beta[col] - mu * sc);
  }
}

// ============ final normalize from coeff, M=16, fp32 ============
__global__ __launch_bounds__(256) void bnout(const float4* __restrict__ h,
                                             const float* __restrict__ coeff,
                                             float4* __restrict__ out) {
  int t = blockIdx.x * 256 + threadIdx.x;
  if (t >= NN * 4) return;
  float4 v = h[t];
  int j0 = (4 * t) & 15;
  float4 o;
  o.x = fmaf(v.x, coeff[j0 + 0], coeff[16 + j0 + 0]);
  o.y = fmaf(v.y, coeff[j0 + 1], coeff[16 + j0 + 1]);
  o.z = fmaf(v.z, coeff[j0 + 2], coeff[16 + j0 + 2]);
  o.w = fmaf(v.w, coeff[j0 + 3], coeff[16 + j0 + 3]);
  out[t] = o;
}

static inline char* alignup(char* p, size_t a) {
  return (char*)(((uintptr_t)p + a - 1) & ~(uintptr_t)(a - 1));
}

extern "C" void kernel_launch(void* const* d_in, const int* in_sizes, int n_in,
                              void* d_out, int out_size, void* d_ws,
                              size_t ws_size, hipStream_t stream) {
  const float* x = (const float*)d_in[0];
  const float* ea = (const float*)d_in[1];
  const int* ei = (const int*)d_in[2];
  const int* src = ei;
  const int* dst = ei + NE;
  const float* lin_w = (const float*)d_in[3];
  const float* lin_b = (const float*)d_in[4];
  const float* c1_w = (const float*)d_in[5];
  const float* c1_b = (const float*)d_in[6];
  const float* c1_g = (const float*)d_in[7];
  const float* c1_be = (const float*)d_in[8];
  const float* c2_w = (const float*)d_in[9];
  const float* c2_b = (const float*)d_in[10];
  const float* c2_g = (const float*)d_in[11];
  const float* c2_be = (const float*)d_in[12];
  const float* l1_w = (const float*)d_in[13];
  const float* l1_b = (const float*)d_in[14];
  const float* l1_g = (const float*)d_in[15];
  const float* l1_be = (const float*)d_in[16];
  const float* ma_w = (const float*)d_in[17];
  const float* ma_b = (const float*)d_in[18];
  const float* ma_g = (const float*)d_in[19];
  const float* ma_be = (const float*)d_in[20];
  const float* mb_w = (const float*)d_in[21];
  const float* mb_b = (const float*)d_in[22];
  const float* mb_g = (const float*)d_in[23];
  const float* mb_be = (const float*)d_in[24];

  typedef unsigned short us;
  char* p = (char*)d_ws;
  us* xb = (us*)p;   p += (size_t)NN * 96 * 2;
  us* Ab = (us*)p;   p += (size_t)NN * 96 * 2;
  us* H1 = (us*)p;   p += (size_t)NN * 96 * 2;
  us* H2 = (us*)p;   p += (size_t)NN * 64 * 2;
  us* H3 = (us*)p;   p += (size_t)NN * 96 * 2;
  us* H4 = (us*)p;   p += (size_t)NN * 96 * 2;
  float* H5 = (float*)p; p += (size_t)NN * 16 * 4;
  p = alignup(p, 256);
  us* Wz1 = (us*)p;  p += 3 * 6 * 64 * 8 * 2;
  us* Wz2 = (us*)p;  p += 3 * 4 * 64 * 8 * 2;
  us* Wz3 = (us*)p;  p += 5 * 6 * 64 * 8 * 2;
  us* Wz4 = (us*)p;  p += 3 * 6 * 64 * 8 * 2;
  us* Wz5 = (us*)p;  p += 3 * 1 * 64 * 8 * 2;
  p = alignup(p, 256);
  float* bf1 = (float*)p; p += 96 * 4;
  float* bf2 = (float*)p; p += 64 * 4;
  float* bf3 = (float*)p; p += 96 * 4;
  float* bf4 = (float*)p; p += 96 * 4;
  float* bf5 = (float*)p; p += 16 * 4;
  float* co1 = (float*)p; p += 192 * 4;
  float* co2 = (float*)p; p += 128 * 4;
  float* co3 = (float*)p; p += 192 * 4;
  float* co4 = (float*)p; p += 192 * 4;
  float* co5 = (float*)p; p += 32 * 4;
  p = alignup(p, 256);
  float* partial = (float*)p; p += (size_t)GGEMM * 192 * 4;
  p = alignup(p, 256);
  char* zbase = p;
  int* counts = (int*)p;  p += (size_t)NN * 4;
  size_t zbytes = (size_t)(p - zbase);
  int* rowstart = (int*)p; p += (size_t)(NN + 1) * 4;
  int* bsum = (int*)p;    p += 256 * 4;
  int* boff = (int*)p;    p += 256 * 4;
  int* rank = (int*)p;    p += (size_t)NE * 4;
  unsigned* pack = (unsigned*)p; p += (size_t)NE * 4;

  hipMemsetAsync(zbase, 0, zbytes, stream);

  const int eb = (NE + 255) / 256;
  const int n12 = NN * 12;
  const int b12 = (n12 + 255) / 256;
  const int aggG = NN / 4;  // 12500, exact

  // ---- prep ----
  f2bf_k<<<b12, 256, 0, stream>>>(x, xb, n12);
  hist_rank<<<eb, 256, 0, stream>>>(dst, counts, rank);
  scan_part<<<NB, 256, 0, stream>>>(counts, bsum);
  scan_top<<<1, 256, 0, stream>>>(bsum, boff);
  scan_apply<<<NB, 256, 0, stream>>>(counts, boff, rowstart);
  scatter_k<<<eb, 256, 0, stream>>>(src, dst, ea, rowstart, rank, pack);

  // ---- conv1 ----
  agg_wave<<<aggG, 256, 0, stream>>>(xb, lin_w, lin_b, rowstart, pack, Ab);
  wprep<96, 96, 0, 0><<<5, 256, 0, stream>>>(c1_w, c1_b, nullptr, nullptr, Wz1,
                                             bf1);
  gemm_mfma<96, 0, 96, false><<<GGEMM, 256, 0, stream>>>(Ab, nullptr, Wz1, bf1,
                                                         H1, partial);
  bn_red<96><<<96, 256, 0, stream>>>(partial, c1_g, c1_be, co1);

  // ---- conv2 (BN1 coeff applied on the fly to H1) ----
  agg_wave_norm<<<aggG, 256, 0, stream>>>(H1, co1, lin_w, lin_b, rowstart,
                                          pack, Ab);
  wprep<96, 64, 0, 0><<<4, 256, 0, stream>>>(c2_w, c2_b, nullptr, nullptr, Wz2,
                                             bf2);
  gemm_mfma<96, 0, 64, false><<<GGEMM, 256, 0, stream>>>(Ab, nullptr, Wz2, bf2,
                                                         H2, partial);
  bn_red<64><<<64, 256, 0, stream>>>(partial, c2_g, c2_be, co2);

  // ---- lin1 on concat([H1(BN1 folded), H2(BN2 folded)]) ----
  wprep<160, 96, 96, 64><<<8, 256, 0, stream>>>(l1_w, l1_b, co1, co2, Wz3,
                                                bf3);
  gemm_mfma<96, 64, 96, false><<<GGEMM, 256, 0, stream>>>(H1, H2, Wz3, bf3, H3,
                                                          partial);
  bn_red<96><<<96, 256, 0, stream>>>(partial, l1_g, l1_be, co3);

  // ---- mlp1a (BN3 folded) ----
  wprep<96, 96, 96, 0><<<5, 256, 0, stream>>>(ma_w, ma_b, co3, nullptr, Wz4,
                                              bf4);
  gemm_mfma<96, 0, 96, false><<<GGEMM, 256, 0, stream>>>(H3, nullptr, Wz4, bf4,
                                                         H4, partial);
  bn_red<96><<<96, 256, 0, stream>>>(partial, ma_g, ma_be, co4);

  // ---- mlp1b (BN4 folded) -> H5 fp32, then BN5 via bn_red + bnout ----
  wprep<96, 16, 96, 0><<<1, 256, 0, stream>>>(mb_w, mb_b, co4, nullptr, Wz5,
                                              bf5);
  gemm_mfma<96, 0, 16, true><<<GGEMM, 256, 0, stream>>>(H4, nullptr, Wz5, bf5,
                                                        H5, partial);
  bn_red<16><<<16, 256, 0, stream>>>(partial, mb_g, mb_be, co5);
  bnout<<<(NN * 4 + 255) / 256, 256, 0, stream>>>((const float4*)H5, co5,
                                                  (float4*)d_out);
}

// Round 10
// 315.706 us; speedup vs baseline: 2.0129x; 1.0230x over previous
//
#include <hip/hip_runtime.h>

#define NN 50000
#define NE 800000
#define DD 96
#define BN_EPS 1e-5
#define NB 196    // ceil(NN/256)
#define GGEMM 782 // gemm grid: ceil(3125 tiles / 4 waves)
// fused prep kernel block ranges
#define PB_F2BF 2344              // ceil(NN*12/256)
#define PB_HIST (PB_F2BF + 3125)  // + NE/256
#define PB_WP1 (PB_HIST + 5)
#define PB_WP2 (PB_WP1 + 4)

typedef __attribute__((ext_vector_type(8))) short short8v;
typedef __attribute__((ext_vector_type(4))) float float4v;

__device__ inline float bf2f(unsigned u) { return __uint_as_float(u << 16); }
__device__ inline unsigned short f2bf(float f) {
  unsigned u = __float_as_uint(f);
  return (unsigned short)((u + 0x7FFF + ((u >> 16) & 1)) >> 16);
}
__device__ inline void unpack8(uint4 v, float* f) {
  f[0] = bf2f(v.x & 0xffff); f[1] = bf2f(v.x >> 16);
  f[2] = bf2f(v.y & 0xffff); f[3] = bf2f(v.y >> 16);
  f[4] = bf2f(v.z & 0xffff); f[5] = bf2f(v.z >> 16);
  f[6] = bf2f(v.w & 0xffff); f[7] = bf2f(v.w >> 16);
}
__device__ inline uint4 pack8(const float* f) {
  uint4 v;
  v.x = (unsigned)f2bf(f[0]) | ((unsigned)f2bf(f[1]) << 16);
  v.y = (unsigned)f2bf(f[2]) | ((unsigned)f2bf(f[3]) << 16);
  v.z = (unsigned)f2bf(f[4]) | ((unsigned)f2bf(f[5]) << 16);
  v.w = (unsigned)f2bf(f[6]) | ((unsigned)f2bf(f[7]) << 16);
  return v;
}

// wprep body without BN folding (conv1/conv2 weights)
template <int K, int M>
__device__ inline void wprep_plain(const float* __restrict__ W,
                                   const float* __restrict__ b,
                                   unsigned short* __restrict__ Wz,
                                   float* __restrict__ bf, int t) {
  constexpr int KT = K / 32, MT = M / 16;
  if (t < KT * MT * 64) {
    int lane = t & 63, fr = t >> 6;
    int kt = fr / MT, ct = fr - kt * MT;
    int col = ct * 16 + (lane & 15);
    int k0 = kt * 32 + (lane >> 4) * 8;
    float f[8];
#pragma unroll
    for (int j = 0; j < 8; j++) f[j] = W[(k0 + j) * M + col];
    ((uint4*)Wz)[t] = pack8(f);
  } else if (t < KT * MT * 64 + M) {
    int j = t - KT * MT * 64;
    bf[j] = b[j];
  }
}

// ===== fused prep: f2bf(x) | hist+rank | wprep(conv1) | wprep(conv2) =====
__global__ __launch_bounds__(256) void prep_k(
    const float* __restrict__ x, unsigned short* __restrict__ xb,
    const int* __restrict__ dst, int* __restrict__ counts,
    int* __restrict__ rank, const float* __restrict__ c1_w,
    const float* __restrict__ c1_b, unsigned short* __restrict__ Wz1,
    float* __restrict__ bf1, const float* __restrict__ c2_w,
    const float* __restrict__ c2_b, unsigned short* __restrict__ Wz2,
    float* __restrict__ bf2) {
  int bid = blockIdx.x;
  int tid = threadIdx.x;
  if (bid < PB_F2BF) {
    int t = bid * 256 + tid;
    if (t < NN * 12) {
      const float4* p = (const float4*)x + 2 * t;
      float4 a = p[0], b = p[1];
      float f[8] = {a.x, a.y, a.z, a.w, b.x, b.y, b.z, b.w};
      ((uint4*)xb)[t] = pack8(f);
    }
  } else if (bid < PB_HIST) {
    int e = (bid - PB_F2BF) * 256 + tid;
    if (e < NE) rank[e] = atomicAdd(&counts[dst[e]], 1);
  } else if (bid < PB_WP1) {
    wprep_plain<96, 96>(c1_w, c1_b, Wz1, bf1, (bid - PB_HIST) * 256 + tid);
  } else {
    wprep_plain<96, 64>(c2_w, c2_b, Wz2, bf2, (bid - PB_WP1) * 256 + tid);
  }
}

__global__ __launch_bounds__(256) void scan_part(const int* __restrict__ counts,
                                                 int* __restrict__ bsum) {
  __shared__ int s[256];
  int tid = threadIdx.x;
  int i = blockIdx.x * 256 + tid;
  s[tid] = (i < NN) ? counts[i] : 0;
  __syncthreads();
  for (int st = 128; st > 0; st >>= 1) {
    if (tid < st) s[tid] += s[tid + st];
    __syncthreads();
  }
  if (tid == 0) bsum[blockIdx.x] = s[0];
}

__global__ __launch_bounds__(256) void scan_top(const int* __restrict__ bsum,
                                                int* __restrict__ boff) {
  __shared__ int s[256];
  int tid = threadIdx.x;
  int v = (tid < NB) ? bsum[tid] : 0;
  s[tid] = v;
  __syncthreads();
  for (int off = 1; off < 256; off <<= 1) {
    int t = (tid >= off) ? s[tid - off] : 0;
    __syncthreads();
    s[tid] += t;
    __syncthreads();
  }
  if (tid < NB) boff[tid] = s[tid] - v;
}

__global__ __launch_bounds__(256) void scan_apply(
    const int* __restrict__ counts, const int* __restrict__ boff,
    int* __restrict__ rowstart) {
  __shared__ int s[256];
  int tid = threadIdx.x;
  int i = blockIdx.x * 256 + tid;
  int v = (i < NN) ? counts[i] : 0;
  s[tid] = v;
  __syncthreads();
  for (int off = 1; off < 256; off <<= 1) {
    int t = (tid >= off) ? s[tid - off] : 0;
    __syncthreads();
    s[tid] += t;
    __syncthreads();
  }
  if (i < NN) rowstart[i] = boff[blockIdx.x] + s[tid] - v;
  if (i == 0) rowstart[NN] = NE;
}

// pack entry: low 16 = src node (NN<65536), high 16 = ea as bf16
__global__ __launch_bounds__(256) void scatter_k(
    const int* __restrict__ src, const int* __restrict__ dst,
    const float* __restrict__ ea, const int* __restrict__ rowstart,
    const int* __restrict__ rank, unsigned* __restrict__ pack) {
  int e = blockIdx.x * 256 + threadIdx.x;
  if (e >= NE) return;
  int p = rowstart[dst[e]] + rank[e];
  pack[p] = (unsigned)src[e] | ((unsigned)f2bf(ea[e]) << 16);
}

// ===== wave-per-node CSR aggregation: lane = (c8, es), 2x5 edges in flight ===
__global__ __launch_bounds__(256) void agg_wave(
    const unsigned short* __restrict__ xin, const float* __restrict__ lw,
    const float* __restrict__ lb, const int* __restrict__ rowstart,
    const unsigned* __restrict__ pack, unsigned short* __restrict__ out) {
  int n = blockIdx.x * 4 + (threadIdx.x >> 6);  // grid exactly NN/4
  int lane = threadIdx.x & 63;
  int es = lane / 12;       // 0..5 (es==5 idle)
  int c8 = lane - es * 12;  // 0..11
  float lwv[8], lbv[8], acc[8];
#pragma unroll
  for (int i = 0; i < 8; i++) {
    lwv[i] = lw[c8 * 8 + i];
    lbv[i] = lb[c8 * 8 + i];
    acc[i] = 0.f;
  }
  if (es == 0) {
    uint4 xo = *(const uint4*)(xin + (size_t)n * DD + c8 * 8);
    unpack8(xo, acc);
  }
  int beg = rowstart[n], end = rowstart[n + 1];
  if (lane < 60) {
    int i = beg + es;
    for (; i + 5 < end; i += 10) {
      unsigned pk0 = pack[i], pk1 = pack[i + 5];
      float ev0 = bf2f(pk0 >> 16), ev1 = bf2f(pk1 >> 16);
      uint4 xv0 = *(const uint4*)(xin + (size_t)(pk0 & 0xffff) * DD + c8 * 8);
      uint4 xv1 = *(const uint4*)(xin + (size_t)(pk1 & 0xffff) * DD + c8 * 8);
      float xs0[8], xs1[8];
      unpack8(xv0, xs0);
      unpack8(xv1, xs1);
#pragma unroll
      for (int j = 0; j < 8; j++) {
        acc[j] += fmaxf(xs0[j] + fmaf(ev0, lwv[j], lbv[j]), 0.0f);
        acc[j] += fmaxf(xs1[j] + fmaf(ev1, lwv[j], lbv[j]), 0.0f);
      }
    }
    if (i < end) {
      unsigned pk = pack[i];
      float ev = bf2f(pk >> 16);
      uint4 xv = *(const uint4*)(xin + (size_t)(pk & 0xffff) * DD + c8 * 8);
      float xs[8];
      unpack8(xv, xs);
#pragma unroll
      for (int j = 0; j < 8; j++)
        acc[j] += fmaxf(xs[j] + fmaf(ev, lwv[j], lbv[j]), 0.0f);
    }
  }
#pragma unroll
  for (int j = 0; j < 8; j++) {
    float a = acc[j];
    float t1 = __shfl_down(a, 12);
    float t2 = __shfl_down(a, 24);
    float t3 = __shfl_down(a, 36);
    float t4 = __shfl_down(a, 48);
    acc[j] = a + t1 + t2 + t3 + t4;
  }
  if (es == 0)
    *(uint4*)(out + (size_t)n * DD + c8 * 8) = pack8(acc);
}

// ===== same, with BN affine (precomputed coeff) applied on the fly =====
__global__ __launch_bounds__(256) void agg_wave_norm(
    const unsigned short* __restrict__ h, const float* __restrict__ coeff,
    const float* __restrict__ lw, const float* __restrict__ lb,
    const int* __restrict__ rowstart, const unsigned* __restrict__ pack,
    unsigned short* __restrict__ out) {
  int n = blockIdx.x * 4 + (threadIdx.x >> 6);
  int lane = threadIdx.x & 63;
  int es = lane / 12;
  int c8 = lane - es * 12;
  float sc[8], tsh[8], tlb[8], lwv[8], acc[8];
#pragma unroll
  for (int i = 0; i < 8; i++) {
    sc[i] = coeff[c8 * 8 + i];
    tsh[i] = coeff[96 + c8 * 8 + i];
    tlb[i] = tsh[i] + lb[c8 * 8 + i];
    lwv[i] = lw[c8 * 8 + i];
    acc[i] = 0.f;
  }
  if (es == 0) {
    uint4 xo = *(const uint4*)(h + (size_t)n * DD + c8 * 8);
    float f[8];
    unpack8(xo, f);
#pragma unroll
    for (int i = 0; i < 8; i++) acc[i] = fmaf(sc[i], f[i], tsh[i]);
  }
  int beg = rowstart[n], end = rowstart[n + 1];
  if (lane < 60) {
    int i = beg + es;
    for (; i + 5 < end; i += 10) {
      unsigned pk0 = pack[i], pk1 = pack[i + 5];
      float ev0 = bf2f(pk0 >> 16), ev1 = bf2f(pk1 >> 16);
      uint4 xv0 = *(const uint4*)(h + (size_t)(pk0 & 0xffff) * DD + c8 * 8);
      uint4 xv1 = *(const uint4*)(h + (size_t)(pk1 & 0xffff) * DD + c8 * 8);
      float xs0[8], xs1[8];
      unpack8(xv0, xs0);
      unpack8(xv1, xs1);
#pragma unroll
      for (int j = 0; j < 8; j++) {
        acc[j] += fmaxf(fmaf(sc[j], xs0[j], fmaf(ev0, lwv[j], tlb[j])), 0.0f);
        acc[j] += fmaxf(fmaf(sc[j], xs1[j], fmaf(ev1, lwv[j], tlb[j])), 0.0f);
      }
    }
    if (i < end) {
      unsigned pk = pack[i];
      float ev = bf2f(pk >> 16);
      uint4 xv = *(const uint4*)(h + (size_t)(pk & 0xffff) * DD + c8 * 8);
      float xs[8];
      unpack8(xv, xs);
#pragma unroll
      for (int j = 0; j < 8; j++)
        acc[j] += fmaxf(fmaf(sc[j], xs[j], fmaf(ev, lwv[j], tlb[j])), 0.0f);
    }
  }
#pragma unroll
  for (int j = 0; j < 8; j++) {
    float a = acc[j];
    float t1 = __shfl_down(a, 12);
    float t2 = __shfl_down(a, 24);
    float t3 = __shfl_down(a, 36);
    float t4 = __shfl_down(a, 48);
    acc[j] = a + t1 + t2 + t3 + t4;
  }
  if (es == 0)
    *(uint4*)(out + (size_t)n * DD + c8 * 8) = pack8(acc);
}

// ============ W prep with BN folding (layers 3-5) ============
// cA layout: scale[0..KA), shift[KA..2KA); cB: scale[0..KB), shift[KB..2KB)
template <int K, int M, int KA, int KB>
__global__ __launch_bounds__(256) void wprep(const float* __restrict__ W,
                                             const float* __restrict__ b,
                                             const float* __restrict__ cA,
                                             const float* __restrict__ cB,
                                             unsigned short* __restrict__ Wz,
                                             float* __restrict__ bf) {
  constexpr int KT = K / 32, MT = M / 16;
  int t = blockIdx.x * 256 + threadIdx.x;
  if (t < KT * MT * 64) {
    int lane = t & 63, fr = t >> 6;
    int kt = fr / MT, ct = fr - kt * MT;
    int col = ct * 16 + (lane & 15);
    int k0 = kt * 32 + (lane >> 4) * 8;
    float f[8];
#pragma unroll
    for (int j = 0; j < 8; j++) {
      int k = k0 + j;
      float w = W[k * M + col];
      if (KA > 0 && k < KA) w *= cA[k];
      if (KB > 0 && k >= KA && k < KA + KB) w *= cB[k - KA];
      f[j] = w;
    }
    ((uint4*)Wz)[t] = pack8(f);
  } else if (t < KT * MT * 64 + M) {
    int j = t - KT * MT * 64;
    float acc = b[j];
    if (KA > 0)
      for (int k = 0; k < KA; k++) acc += cA[KA + k] * W[k * M + j];
    if (KB > 0)
      for (int k = 0; k < KB; k++) acc += cB[KB + k] * W[(KA + k) * M + j];
    bf[j] = acc;
  }
}

// ============ MFMA GEMM + bias + relu + per-block column stats ============
template <int K1, int K2, int M, bool OUTF32>
__global__ __launch_bounds__(256) void gemm_mfma(
    const unsigned short* __restrict__ A1,
    const unsigned short* __restrict__ A2,
    const unsigned short* __restrict__ Wz, const float* __restrict__ bias,
    void* __restrict__ hOut, float* __restrict__ partial) {
  constexpr int K = K1 + K2;
  constexpr int KT = K / 32;
  constexpr int MT = M / 16;
  constexpr int NT = NN / 16;  // 3125
  int tid = threadIdx.x;
  int wave = tid >> 6, lane = tid & 63;
  int lr = lane & 15, lk = lane >> 4;

  float bj[MT], s[MT], q[MT];
#pragma unroll
  for (int ct = 0; ct < MT; ct++) {
    bj[ct] = bias[ct * 16 + lr];
    s[ct] = 0.f;
    q[ct] = 0.f;
  }

  for (int tt = blockIdx.x * 4 + wave; tt < NT; tt += gridDim.x * 4) {
    float4v acc[MT];
#pragma unroll
    for (int ct = 0; ct < MT; ct++) acc[ct] = (float4v){0.f, 0.f, 0.f, 0.f};

    const unsigned short* a1 = A1 + (size_t)(tt * 16 + lr) * K1 + lk * 8;
    const unsigned short* a2 =
        (K2 > 0) ? A2 + (size_t)(tt * 16 + lr) * K2 + lk * 8 : a1;
#pragma unroll
    for (int kt = 0; kt < KT; kt++) {
      short8v av;
      if (kt * 32 < K1)
        av = *reinterpret_cast<const short8v*>(a1 + kt * 32);
      else
        av = *reinterpret_cast<const short8v*>(a2 + (kt * 32 - K1));
#pragma unroll
      for (int ct = 0; ct < MT; ct++) {
        short8v bv = *reinterpret_cast<const short8v*>(
            Wz + ((size_t)(kt * MT + ct) * 64 + lane) * 8);
        acc[ct] =
            __builtin_amdgcn_mfma_f32_16x16x32_bf16(av, bv, acc[ct], 0, 0, 0);
      }
    }
#pragma unroll
    for (int ct = 0; ct < MT; ct++) {
#pragma unroll
      for (int i = 0; i < 4; i++) {
        float o = fmaxf(acc[ct][i] + bj[ct], 0.f);
        size_t row = (size_t)tt * 16 + lk * 4 + i;
        if (OUTF32)
          ((float*)hOut)[row * M + ct * 16 + lr] = o;
        else
          ((unsigned short*)hOut)[row * M + ct * 16 + lr] = f2bf(o);
        s[ct] += o;
        q[ct] += o * o;
      }
    }
  }

  __shared__ float sred[4][M], qred[4][M];
#pragma unroll
  for (int ct = 0; ct < MT; ct++) {
    float ss = s[ct], qq = q[ct];
    ss += __shfl_xor(ss, 16);
    ss += __shfl_xor(ss, 32);
    qq += __shfl_xor(qq, 16);
    qq += __shfl_xor(qq, 32);
    if (lk == 0) {
      sred[wave][ct * 16 + lr] = ss;
      qred[wave][ct * 16 + lr] = qq;
    }
  }
  __syncthreads();
  if (tid < M) {
    partial[(size_t)blockIdx.x * (2 * M) + tid] =
        sred[0][tid] + sred[1][tid] + sred[2][tid] + sred[3][tid];
  } else if (tid < 2 * M) {
    int j = tid - M;
    partial[(size_t)blockIdx.x * (2 * M) + tid] =
        qred[0][j] + qred[1][j] + qred[2][j] + qred[3][j];
  }
}

// ==== reduce partials -> BN coeff: one block per column ====
template <int M>
__global__ __launch_bounds__(256) void bn_red(const float* __restrict__ partial,
                                              const float* __restrict__ g,
                                              const float* __restrict__ beta,
                                              float* __restrict__ coeff) {
  __shared__ double ls[256], lq[256];
  int col = blockIdx.x;  // 0..M-1
  int tid = threadIdx.x;
  double s = 0.0, q = 0.0;
  for (int b = tid; b < GGEMM; b += 256) {
    const float* row = partial + (size_t)b * (2 * M);
    s += row[col];
    q += row[M + col];
  }
  ls[tid] = s;
  lq[tid] = q;
  __syncthreads();
  for (int st = 128; st > 0; st >>= 1) {
    if (tid < st) {
      ls[tid] += ls[tid + st];
      lq[tid] += lq[tid + st];
    }
    __syncthreads();
  }
  if (tid == 0) {
    double mu = ls[0] / (double)NN;
    double var = lq[0] / (double)NN - mu * mu;
    double inv = 1.0 / sqrt(var + (double)BN_EPS);
    double sc = (double)g[col] * inv;
    coeff[col] = (float)sc;
    coeff[M + col] = (float)((double)beta[col] - mu * sc);
  }
}

// ============ final normalize from coeff, M=16, fp32 ============
__global__ __launch_bounds__(256) void bnout(const float4* __restrict__ h,
                                             const float* __restrict__ coeff,
                                             float4* __restrict__ out) {
  int t = blockIdx.x * 256 + threadIdx.x;
  if (t >= NN * 4) return;
  float4 v = h[t];
  int j0 = (4 * t) & 15;
  float4 o;
  o.x = fmaf(v.x, coeff[j0 + 0], coeff[16 + j0 + 0]);
  o.y = fmaf(v.y, coeff[j0 + 1], coeff[16 + j0 + 1]);
  o.z = fmaf(v.z, coeff[j0 + 2], coeff[16 + j0 + 2]);
  o.w = fmaf(v.w, coeff[j0 + 3], coeff[16 + j0 + 3]);
  out[t] = o;
}

static inline char* alignup(char* p, size_t a) {
  return (char*)(((uintptr_t)p + a - 1) & ~(uintptr_t)(a - 1));
}

extern "C" void kernel_launch(void* const* d_in, const int* in_sizes, int n_in,
                              void* d_out, int out_size, void* d_ws,
                              size_t ws_size, hipStream_t stream) {
  const float* x = (const float*)d_in[0];
  const float* ea = (const float*)d_in[1];
  const int* ei = (const int*)d_in[2];
  const int* src = ei;
  const int* dst = ei + NE;
  const float* lin_w = (const float*)d_in[3];
  const float* lin_b = (const float*)d_in[4];
  const float* c1_w = (const float*)d_in[5];
  const float* c1_b = (const float*)d_in[6];
  const float* c1_g = (const float*)d_in[7];
  const float* c1_be = (const float*)d_in[8];
  const float* c2_w = (const float*)d_in[9];
  const float* c2_b = (const float*)d_in[10];
  const float* c2_g = (const float*)d_in[11];
  const float* c2_be = (const float*)d_in[12];
  const float* l1_w = (const float*)d_in[13];
  const float* l1_b = (const float*)d_in[14];
  const float* l1_g = (const float*)d_in[15];
  const float* l1_be = (const float*)d_in[16];
  const float* ma_w = (const float*)d_in[17];
  const float* ma_b = (const float*)d_in[18];
  const float* ma_g = (const float*)d_in[19];
  const float* ma_be = (const float*)d_in[20];
  const float* mb_w = (const float*)d_in[21];
  const float* mb_b = (const float*)d_in[22];
  const float* mb_g = (const float*)d_in[23];
  const float* mb_be = (const float*)d_in[24];

  typedef unsigned short us;
  char* p = (char*)d_ws;
  us* xb = (us*)p;   p += (size_t)NN * 96 * 2;
  us* Ab = (us*)p;   p += (size_t)NN * 96 * 2;
  us* H1 = (us*)p;   p += (size_t)NN * 96 * 2;
  us* H2 = (us*)p;   p += (size_t)NN * 64 * 2;
  us* H3 = (us*)p;   p += (size_t)NN * 96 * 2;
  us* H4 = (us*)p;   p += (size_t)NN * 96 * 2;
  float* H5 = (float*)p; p += (size_t)NN * 16 * 4;
  p = alignup(p, 256);
  us* Wz1 = (us*)p;  p += 3 * 6 * 64 * 8 * 2;
  us* Wz2 = (us*)p;  p += 3 * 4 * 64 * 8 * 2;
  us* Wz3 = (us*)p;  p += 5 * 6 * 64 * 8 * 2;
  us* Wz4 = (us*)p;  p += 3 * 6 * 64 * 8 * 2;
  us* Wz5 = (us*)p;  p += 3 * 1 * 64 * 8 * 2;
  p = alignup(p, 256);
  float* bf1 = (float*)p; p += 96 * 4;
  float* bf2 = (float*)p; p += 64 * 4;
  float* bf3 = (float*)p; p += 96 * 4;
  float* bf4 = (float*)p; p += 96 * 4;
  float* bf5 = (float*)p; p += 16 * 4;
  float* co1 = (float*)p; p += 192 * 4;
  float* co2 = (float*)p; p += 128 * 4;
  float* co3 = (float*)p; p += 192 * 4;
  float* co4 = (float*)p; p += 192 * 4;
  float* co5 = (float*)p; p += 32 * 4;
  p = alignup(p, 256);
  float* partial = (float*)p; p += (size_t)GGEMM * 192 * 4;
  p = alignup(p, 256);
  char* zbase = p;
  int* counts = (int*)p;  p += (size_t)NN * 4;
  size_t zbytes = (size_t)(p - zbase);
  int* rowstart = (int*)p; p += (size_t)(NN + 1) * 4;
  int* bsum = (int*)p;    p += 256 * 4;
  int* boff = (int*)p;    p += 256 * 4;
  int* rank = (int*)p;    p += (size_t)NE * 4;
  unsigned* pack = (unsigned*)p; p += (size_t)NE * 4;

  hipMemsetAsync(zbase, 0, zbytes, stream);

  const int eb = (NE + 255) / 256;
  const int aggG = NN / 4;  // 12500, exact

  // ---- fused prep: f2bf | hist+rank | wprep1 | wprep2 ----
  prep_k<<<PB_WP2, 256, 0, stream>>>(x, xb, dst, counts, rank, c1_w, c1_b, Wz1,
                                     bf1, c2_w, c2_b, Wz2, bf2);
  scan_part<<<NB, 256, 0, stream>>>(counts, bsum);
  scan_top<<<1, 256, 0, stream>>>(bsum, boff);
  scan_apply<<<NB, 256, 0, stream>>>(counts, boff, rowstart);
  scatter_k<<<eb, 256, 0, stream>>>(src, dst, ea, rowstart, rank, pack);

  // ---- conv1 ----
  agg_wave<<<aggG, 256, 0, stream>>>(xb, lin_w, lin_b, rowstart, pack, Ab);
  gemm_mfma<96, 0, 96, false><<<GGEMM, 256, 0, stream>>>(Ab, nullptr, Wz1, bf1,
                                                         H1, partial);
  bn_red<96><<<96, 256, 0, stream>>>(partial, c1_g, c1_be, co1);

  // ---- conv2 (BN1 coeff applied on the fly to H1) ----
  agg_wave_norm<<<aggG, 256, 0, stream>>>(H1, co1, lin_w, lin_b, rowstart,
                                          pack, Ab);
  gemm_mfma<96, 0, 64, false><<<GGEMM, 256, 0, stream>>>(Ab, nullptr, Wz2, bf2,
                                                         H2, partial);
  bn_red<64><<<64, 256, 0, stream>>>(partial, c2_g, c2_be, co2);

  // ---- lin1 on concat([H1(BN1 folded), H2(BN2 folded)]) ----
  wprep<160, 96, 96, 64><<<8, 256, 0, stream>>>(l1_w, l1_b, co1, co2, Wz3,
                                                bf3);
  gemm_mfma<96, 64, 96, false><<<GGEMM, 256, 0, stream>>>(H1, H2, Wz3, bf3, H3,
                                                          partial);
  bn_red<96><<<96, 256, 0, stream>>>(partial, l1_g, l1_be, co3);

  // ---- mlp1a (BN3 folded) ----
  wprep<96, 96, 96, 0><<<5, 256, 0, stream>>>(ma_w, ma_b, co3, nullptr, Wz4,
                                              bf4);
  gemm_mfma<96, 0, 96, false><<<GGEMM, 256, 0, stream>>>(H3, nullptr, Wz4, bf4,
                                                         H4, partial);
  bn_red<96><<<96, 256, 0, stream>>>(partial, ma_g, ma_be, co4);

  // ---- mlp1b (BN4 folded) -> H5 fp32, then BN5 via bn_red + bnout ----
  wprep<96, 16, 96, 0><<<1, 256, 0, stream>>>(mb_w, mb_b, co4, nullptr, Wz5,
                                              bf5);
  gemm_mfma<96, 0, 16, true><<<GGEMM, 256, 0, stream>>>(H4, nullptr, Wz5, bf5,
                                                        H5, partial);
  bn_red<16><<<16, 256, 0, stream>>>(partial, mb_g, mb_be, co5);
  bnout<<<(NN * 4 + 255) / 256, 256, 0, stream>>>((const float4*)H5, co5,
                                                  (float4*)d_out);
}

// Round 11
// 312.505 us; speedup vs baseline: 2.0335x; 1.0102x over previous
//
#include <hip/hip_runtime.h>

#define NN 50000
#define NE 800000
#define DD 96
#define BN_EPS 1e-5
#define NB 196    // ceil(NN/256)
#define GGEMM 782 // gemm grid: ceil(3125 tiles / 4 waves)
// fused prep kernel block ranges
#define PB_F2BF 2344              // ceil(NN*12/256)
#define PB_HIST (PB_F2BF + 3125)  // + NE/256
#define PB_WP1 (PB_HIST + 5)
#define PB_WP2 (PB_WP1 + 4)

typedef __attribute__((ext_vector_type(8))) short short8v;
typedef __attribute__((ext_vector_type(4))) float float4v;

__device__ inline float bf2f(unsigned u) { return __uint_as_float(u << 16); }
__device__ inline unsigned short f2bf(float f) {
  unsigned u = __float_as_uint(f);
  return (unsigned short)((u + 0x7FFF + ((u >> 16) & 1)) >> 16);
}
__device__ inline void unpack8(uint4 v, float* f) {
  f[0] = bf2f(v.x & 0xffff); f[1] = bf2f(v.x >> 16);
  f[2] = bf2f(v.y & 0xffff); f[3] = bf2f(v.y >> 16);
  f[4] = bf2f(v.z & 0xffff); f[5] = bf2f(v.z >> 16);
  f[6] = bf2f(v.w & 0xffff); f[7] = bf2f(v.w >> 16);
}
__device__ inline uint4 pack8(const float* f) {
  uint4 v;
  v.x = (unsigned)f2bf(f[0]) | ((unsigned)f2bf(f[1]) << 16);
  v.y = (unsigned)f2bf(f[2]) | ((unsigned)f2bf(f[3]) << 16);
  v.z = (unsigned)f2bf(f[4]) | ((unsigned)f2bf(f[5]) << 16);
  v.w = (unsigned)f2bf(f[6]) | ((unsigned)f2bf(f[7]) << 16);
  return v;
}

// wprep body without BN folding (conv1/conv2 weights)
template <int K, int M>
__device__ inline void wprep_plain(const float* __restrict__ W,
                                   const float* __restrict__ b,
                                   unsigned short* __restrict__ Wz,
                                   float* __restrict__ bf, int t) {
  constexpr int KT = K / 32, MT = M / 16;
  if (t < KT * MT * 64) {
    int lane = t & 63, fr = t >> 6;
    int kt = fr / MT, ct = fr - kt * MT;
    int col = ct * 16 + (lane & 15);
    int k0 = kt * 32 + (lane >> 4) * 8;
    float f[8];
#pragma unroll
    for (int j = 0; j < 8; j++) f[j] = W[(k0 + j) * M + col];
    ((uint4*)Wz)[t] = pack8(f);
  } else if (t < KT * MT * 64 + M) {
    int j = t - KT * MT * 64;
    bf[j] = b[j];
  }
}

// ===== fused prep: f2bf(x) | hist+rank(u16) | wprep(conv1) | wprep(conv2) ===
__global__ __launch_bounds__(256) void prep_k(
    const float* __restrict__ x, unsigned short* __restrict__ xb,
    const int* __restrict__ dst, int* __restrict__ counts,
    unsigned short* __restrict__ rank, const float* __restrict__ c1_w,
    const float* __restrict__ c1_b, unsigned short* __restrict__ Wz1,
    float* __restrict__ bf1, const float* __restrict__ c2_w,
    const float* __restrict__ c2_b, unsigned short* __restrict__ Wz2,
    float* __restrict__ bf2) {
  int bid = blockIdx.x;
  int tid = threadIdx.x;
  if (bid < PB_F2BF) {
    int t = bid * 256 + tid;
    if (t < NN * 12) {
      const float4* p = (const float4*)x + 2 * t;
      float4 a = p[0], b = p[1];
      float f[8] = {a.x, a.y, a.z, a.w, b.x, b.y, b.z, b.w};
      ((uint4*)xb)[t] = pack8(f);
    }
  } else if (bid < PB_HIST) {
    int e = (bid - PB_F2BF) * 256 + tid;
    if (e < NE)
      rank[e] = (unsigned short)atomicAdd(&counts[dst[e]], 1);
  } else if (bid < PB_WP1) {
    wprep_plain<96, 96>(c1_w, c1_b, Wz1, bf1, (bid - PB_HIST) * 256 + tid);
  } else {
    wprep_plain<96, 64>(c2_w, c2_b, Wz2, bf2, (bid - PB_WP1) * 256 + tid);
  }
}

__global__ __launch_bounds__(256) void scan_part(const int* __restrict__ counts,
                                                 int* __restrict__ bsum) {
  __shared__ int s[256];
  int tid = threadIdx.x;
  int i = blockIdx.x * 256 + tid;
  s[tid] = (i < NN) ? counts[i] : 0;
  __syncthreads();
  for (int st = 128; st > 0; st >>= 1) {
    if (tid < st) s[tid] += s[tid + st];
    __syncthreads();
  }
  if (tid == 0) bsum[blockIdx.x] = s[0];
}

// scan_apply with inlined top-level offset (sum of bsum[0..bid))
__global__ __launch_bounds__(256) void scan_apply(
    const int* __restrict__ counts, const int* __restrict__ bsum,
    int* __restrict__ rowstart) {
  __shared__ int sb[256];
  __shared__ int s[256];
  int tid = threadIdx.x;
  int bid = blockIdx.x;
  sb[tid] = (tid < bid) ? bsum[tid] : 0;  // NB=196 <= 256
  __syncthreads();
  for (int st = 128; st > 0; st >>= 1) {
    if (tid < st) sb[tid] += sb[tid + st];
    __syncthreads();
  }
  int boff = sb[0];
  int i = bid * 256 + tid;
  int v = (i < NN) ? counts[i] : 0;
  s[tid] = v;
  __syncthreads();
  for (int off = 1; off < 256; off <<= 1) {
    int t = (tid >= off) ? s[tid - off] : 0;
    __syncthreads();
    s[tid] += t;
    __syncthreads();
  }
  if (i < NN) rowstart[i] = boff + s[tid] - v;
  if (i == 0) rowstart[NN] = NE;
}

// pack entry: low 16 = src node (NN<65536), high 16 = ea as bf16
__global__ __launch_bounds__(256) void scatter_k(
    const int* __restrict__ src, const int* __restrict__ dst,
    const float* __restrict__ ea, const int* __restrict__ rowstart,
    const unsigned short* __restrict__ rank, unsigned* __restrict__ pack) {
  int e = blockIdx.x * 256 + threadIdx.x;
  if (e >= NE) return;
  int p = rowstart[dst[e]] + (int)rank[e];
  pack[p] = (unsigned)src[e] | ((unsigned)f2bf(ea[e]) << 16);
}

// ===== wave-per-node CSR aggregation: lane = (c8, es), 2x5 edges in flight ===
__global__ __launch_bounds__(256) void agg_wave(
    const unsigned short* __restrict__ xin, const float* __restrict__ lw,
    const float* __restrict__ lb, const int* __restrict__ rowstart,
    const unsigned* __restrict__ pack, unsigned short* __restrict__ out) {
  int n = blockIdx.x * 4 + (threadIdx.x >> 6);  // grid exactly NN/4
  int lane = threadIdx.x & 63;
  int es = lane / 12;       // 0..5 (es==5 idle)
  int c8 = lane - es * 12;  // 0..11
  float lwv[8], lbv[8], acc[8];
#pragma unroll
  for (int i = 0; i < 8; i++) {
    lwv[i] = lw[c8 * 8 + i];
    lbv[i] = lb[c8 * 8 + i];
    acc[i] = 0.f;
  }
  if (es == 0) {
    uint4 xo = *(const uint4*)(xin + (size_t)n * DD + c8 * 8);
    unpack8(xo, acc);
  }
  int beg = rowstart[n], end = rowstart[n + 1];
  if (lane < 60) {
    int i = beg + es;
    for (; i + 5 < end; i += 10) {
      unsigned pk0 = pack[i], pk1 = pack[i + 5];
      float ev0 = bf2f(pk0 >> 16), ev1 = bf2f(pk1 >> 16);
      uint4 xv0 = *(const uint4*)(xin + (size_t)(pk0 & 0xffff) * DD + c8 * 8);
      uint4 xv1 = *(const uint4*)(xin + (size_t)(pk1 & 0xffff) * DD + c8 * 8);
      float xs0[8], xs1[8];
      unpack8(xv0, xs0);
      unpack8(xv1, xs1);
#pragma unroll
      for (int j = 0; j < 8; j++) {
        acc[j] += fmaxf(xs0[j] + fmaf(ev0, lwv[j], lbv[j]), 0.0f);
        acc[j] += fmaxf(xs1[j] + fmaf(ev1, lwv[j], lbv[j]), 0.0f);
      }
    }
    if (i < end) {
      unsigned pk = pack[i];
      float ev = bf2f(pk >> 16);
      uint4 xv = *(const uint4*)(xin + (size_t)(pk & 0xffff) * DD + c8 * 8);
      float xs[8];
      unpack8(xv, xs);
#pragma unroll
      for (int j = 0; j < 8; j++)
        acc[j] += fmaxf(xs[j] + fmaf(ev, lwv[j], lbv[j]), 0.0f);
    }
  }
#pragma unroll
  for (int j = 0; j < 8; j++) {
    float a = acc[j];
    float t1 = __shfl_down(a, 12);
    float t2 = __shfl_down(a, 24);
    float t3 = __shfl_down(a, 36);
    float t4 = __shfl_down(a, 48);
    acc[j] = a + t1 + t2 + t3 + t4;
  }
  if (es == 0)
    *(uint4*)(out + (size_t)n * DD + c8 * 8) = pack8(acc);
}

// ===== same, with BN affine (precomputed coeff) applied on the fly =====
__global__ __launch_bounds__(256) void agg_wave_norm(
    const unsigned short* __restrict__ h, const float* __restrict__ coeff,
    const float* __restrict__ lw, const float* __restrict__ lb,
    const int* __restrict__ rowstart, const unsigned* __restrict__ pack,
    unsigned short* __restrict__ out) {
  int n = blockIdx.x * 4 + (threadIdx.x >> 6);
  int lane = threadIdx.x & 63;
  int es = lane / 12;
  int c8 = lane - es * 12;
  float sc[8], tsh[8], tlb[8], lwv[8], acc[8];
#pragma unroll
  for (int i = 0; i < 8; i++) {
    sc[i] = coeff[c8 * 8 + i];
    tsh[i] = coeff[96 + c8 * 8 + i];
    tlb[i] = tsh[i] + lb[c8 * 8 + i];
    lwv[i] = lw[c8 * 8 + i];
    acc[i] = 0.f;
  }
  if (es == 0) {
    uint4 xo = *(const uint4*)(h + (size_t)n * DD + c8 * 8);
    float f[8];
    unpack8(xo, f);
#pragma unroll
    for (int i = 0; i < 8; i++) acc[i] = fmaf(sc[i], f[i], tsh[i]);
  }
  int beg = rowstart[n], end = rowstart[n + 1];
  if (lane < 60) {
    int i = beg + es;
    for (; i + 5 < end; i += 10) {
      unsigned pk0 = pack[i], pk1 = pack[i + 5];
      float ev0 = bf2f(pk0 >> 16), ev1 = bf2f(pk1 >> 16);
      uint4 xv0 = *(const uint4*)(h + (size_t)(pk0 & 0xffff) * DD + c8 * 8);
      uint4 xv1 = *(const uint4*)(h + (size_t)(pk1 & 0xffff) * DD + c8 * 8);
      float xs0[8], xs1[8];
      unpack8(xv0, xs0);
      unpack8(xv1, xs1);
#pragma unroll
      for (int j = 0; j < 8; j++) {
        acc[j] += fmaxf(fmaf(sc[j], xs0[j], fmaf(ev0, lwv[j], tlb[j])), 0.0f);
        acc[j] += fmaxf(fmaf(sc[j], xs1[j], fmaf(ev1, lwv[j], tlb[j])), 0.0f);
      }
    }
    if (i < end) {
      unsigned pk = pack[i];
      float ev = bf2f(pk >> 16);
      uint4 xv = *(const uint4*)(h + (size_t)(pk & 0xffff) * DD + c8 * 8);
      float xs[8];
      unpack8(xv, xs);
#pragma unroll
      for (int j = 0; j < 8; j++)
        acc[j] += fmaxf(fmaf(sc[j], xs[j], fmaf(ev, lwv[j], tlb[j])), 0.0f);
    }
  }
#pragma unroll
  for (int j = 0; j < 8; j++) {
    float a = acc[j];
    float t1 = __shfl_down(a, 12);
    float t2 = __shfl_down(a, 24);
    float t3 = __shfl_down(a, 36);
    float t4 = __shfl_down(a, 48);
    acc[j] = a + t1 + t2 + t3 + t4;
  }
  if (es == 0)
    *(uint4*)(out + (size_t)n * DD + c8 * 8) = pack8(acc);
}

// ============ W prep with BN folding (layers 3-5) ============
// cA layout: scale[0..KA), shift[KA..2KA); cB: scale[0..KB), shift[KB..2KB)
template <int K, int M, int KA, int KB>
__global__ __launch_bounds__(256) void wprep(const float* __restrict__ W,
                                             const float* __restrict__ b,
                                             const float* __restrict__ cA,
                                             const float* __restrict__ cB,
                                             unsigned short* __restrict__ Wz,
                                             float* __restrict__ bf) {
  constexpr int KT = K / 32, MT = M / 16;
  int t = blockIdx.x * 256 + threadIdx.x;
  if (t < KT * MT * 64) {
    int lane = t & 63, fr = t >> 6;
    int kt = fr / MT, ct = fr - kt * MT;
    int col = ct * 16 + (lane & 15);
    int k0 = kt * 32 + (lane >> 4) * 8;
    float f[8];
#pragma unroll
    for (int j = 0; j < 8; j++) {
      int k = k0 + j;
      float w = W[k * M + col];
      if (KA > 0 && k < KA) w *= cA[k];
      if (KB > 0 && k >= KA && k < KA + KB) w *= cB[k - KA];
      f[j] = w;
    }
    ((uint4*)Wz)[t] = pack8(f);
  } else if (t < KT * MT * 64 + M) {
    int j = t - KT * MT * 64;
    float acc = b[j];
    if (KA > 0)
      for (int k = 0; k < KA; k++) acc += cA[KA + k] * W[k * M + j];
    if (KB > 0)
      for (int k = 0; k < KB; k++) acc += cB[KB + k] * W[(KA + k) * M + j];
    bf[j] = acc;
  }
}

// ============ MFMA GEMM + bias + relu + per-block column stats ============
template <int K1, int K2, int M, bool OUTF32>
__global__ __launch_bounds__(256) void gemm_mfma(
    const unsigned short* __restrict__ A1,
    const unsigned short* __restrict__ A2,
    const unsigned short* __restrict__ Wz, const float* __restrict__ bias,
    void* __restrict__ hOut, float* __restrict__ partial) {
  constexpr int K = K1 + K2;
  constexpr int KT = K / 32;
  constexpr int MT = M / 16;
  constexpr int NT = NN / 16;  // 3125
  int tid = threadIdx.x;
  int wave = tid >> 6, lane = tid & 63;
  int lr = lane & 15, lk = lane >> 4;

  float bj[MT], s[MT], q[MT];
#pragma unroll
  for (int ct = 0; ct < MT; ct++) {
    bj[ct] = bias[ct * 16 + lr];
    s[ct] = 0.f;
    q[ct] = 0.f;
  }

  for (int tt = blockIdx.x * 4 + wave; tt < NT; tt += gridDim.x * 4) {
    float4v acc[MT];
#pragma unroll
    for (int ct = 0; ct < MT; ct++) acc[ct] = (float4v){0.f, 0.f, 0.f, 0.f};

    const unsigned short* a1 = A1 + (size_t)(tt * 16 + lr) * K1 + lk * 8;
    const unsigned short* a2 =
        (K2 > 0) ? A2 + (size_t)(tt * 16 + lr) * K2 + lk * 8 : a1;
#pragma unroll
    for (int kt = 0; kt < KT; kt++) {
      short8v av;
      if (kt * 32 < K1)
        av = *reinterpret_cast<const short8v*>(a1 + kt * 32);
      else
        av = *reinterpret_cast<const short8v*>(a2 + (kt * 32 - K1));
#pragma unroll
      for (int ct = 0; ct < MT; ct++) {
        short8v bv = *reinterpret_cast<const short8v*>(
            Wz + ((size_t)(kt * MT + ct) * 64 + lane) * 8);
        acc[ct] =
            __builtin_amdgcn_mfma_f32_16x16x32_bf16(av, bv, acc[ct], 0, 0, 0);
      }
    }
#pragma unroll
    for (int ct = 0; ct < MT; ct++) {
#pragma unroll
      for (int i = 0; i < 4; i++) {
        float o = fmaxf(acc[ct][i] + bj[ct], 0.f);
        size_t row = (size_t)tt * 16 + lk * 4 + i;
        if (OUTF32)
          ((float*)hOut)[row * M + ct * 16 + lr] = o;
        else
          ((unsigned short*)hOut)[row * M + ct * 16 + lr] = f2bf(o);
        s[ct] += o;
        q[ct] += o * o;
      }
    }
  }

  __shared__ float sred[4][M], qred[4][M];
#pragma unroll
  for (int ct = 0; ct < MT; ct++) {
    float ss = s[ct], qq = q[ct];
    ss += __shfl_xor(ss, 16);
    ss += __shfl_xor(ss, 32);
    qq += __shfl_xor(qq, 16);
    qq += __shfl_xor(qq, 32);
    if (lk == 0) {
      sred[wave][ct * 16 + lr] = ss;
      qred[wave][ct * 16 + lr] = qq;
    }
  }
  __syncthreads();
  if (tid < M) {
    partial[(size_t)blockIdx.x * (2 * M) + tid] =
        sred[0][tid] + sred[1][tid] + sred[2][tid] + sred[3][tid];
  } else if (tid < 2 * M) {
    int j = tid - M;
    partial[(size_t)blockIdx.x * (2 * M) + tid] =
        qred[0][j] + qred[1][j] + qred[2][j] + qred[3][j];
  }
}

// ==== reduce partials -> BN coeff: one block per column ====
template <int M>
__global__ __launch_bounds__(256) void bn_red(const float* __restrict__ partial,
                                              const float* __restrict__ g,
                                              const float* __restrict__ beta,
                                              float* __restrict__ coeff) {
  __shared__ double ls[256], lq[256];
  int col = blockIdx.x;  // 0..M-1
  int tid = threadIdx.x;
  double s = 0.0, q = 0.0;
  for (int b = tid; b < GGEMM; b += 256) {
    const float* row = partial + (size_t)b * (2 * M);
    s += row[col];
    q += row[M + col];
  }
  ls[tid] = s;
  lq[tid] = q;
  __syncthreads();
  for (int st = 128; st > 0; st >>= 1) {
    if (tid < st) {
      ls[tid] += ls[tid + st];
      lq[tid] += lq[tid + st];
    }
    __syncthreads();
  }
  if (tid == 0) {
    double mu = ls[0] / (double)NN;
    double var = lq[0] / (double)NN - mu * mu;
    double inv = 1.0 / sqrt(var + (double)BN_EPS);
    double sc = (double)g[col] * inv;
    coeff[col] = (float)sc;
    coeff[M + col] = (float)((double)beta[col] - mu * sc);
  }
}

// ============ final normalize from coeff, M=16, fp32 ============
__global__ __launch_bounds__(256) void bnout(const float4* __restrict__ h,
                                             const float* __restrict__ coeff,
                                             float4* __restrict__ out) {
  int t = blockIdx.x * 256 + threadIdx.x;
  if (t >= NN * 4) return;
  float4 v = h[t];
  int j0 = (4 * t) & 15;
  float4 o;
  o.x = fmaf(v.x, coeff[j0 + 0], coeff[16 + j0 + 0]);
  o.y = fmaf(v.y, coeff[j0 + 1], coeff[16 + j0 + 1]);
  o.z = fmaf(v.z, coeff[j0 + 2], coeff[16 + j0 + 2]);
  o.w = fmaf(v.w, coeff[j0 + 3], coeff[16 + j0 + 3]);
  out[t] = o;
}

static inline char* alignup(char* p, size_t a) {
  return (char*)(((uintptr_t)p + a - 1) & ~(uintptr_t)(a - 1));
}

extern "C" void kernel_launch(void* const* d_in, const int* in_sizes, int n_in,
                              void* d_out, int out_size, void* d_ws,
                              size_t ws_size, hipStream_t stream) {
  const float* x = (const float*)d_in[0];
  const float* ea = (const float*)d_in[1];
  const int* ei = (const int*)d_in[2];
  const int* src = ei;
  const int* dst = ei + NE;
  const float* lin_w = (const float*)d_in[3];
  const float* lin_b = (const float*)d_in[4];
  const float* c1_w = (const float*)d_in[5];
  const float* c1_b = (const float*)d_in[6];
  const float* c1_g = (const float*)d_in[7];
  const float* c1_be = (const float*)d_in[8];
  const float* c2_w = (const float*)d_in[9];
  const float* c2_b = (const float*)d_in[10];
  const float* c2_g = (const float*)d_in[11];
  const float* c2_be = (const float*)d_in[12];
  const float* l1_w = (const float*)d_in[13];
  const float* l1_b = (const float*)d_in[14];
  const float* l1_g = (const float*)d_in[15];
  const float* l1_be = (const float*)d_in[16];
  const float* ma_w = (const float*)d_in[17];
  const float* ma_b = (const float*)d_in[18];
  const float* ma_g = (const float*)d_in[19];
  const float* ma_be = (const float*)d_in[20];
  const float* mb_w = (const float*)d_in[21];
  const float* mb_b = (const float*)d_in[22];
  const float* mb_g = (const float*)d_in[23];
  const float* mb_be = (const float*)d_in[24];

  typedef unsigned short us;
  char* p = (char*)d_ws;
  us* xb = (us*)p;   p += (size_t)NN * 96 * 2;
  us* Ab = (us*)p;   p += (size_t)NN * 96 * 2;
  us* H1 = (us*)p;   p += (size_t)NN * 96 * 2;
  us* H2 = (us*)p;   p += (size_t)NN * 64 * 2;
  us* H3 = (us*)p;   p += (size_t)NN * 96 * 2;
  us* H4 = (us*)p;   p += (size_t)NN * 96 * 2;
  float* H5 = (float*)p; p += (size_t)NN * 16 * 4;
  p = alignup(p, 256);
  us* Wz1 = (us*)p;  p += 3 * 6 * 64 * 8 * 2;
  us* Wz2 = (us*)p;  p += 3 * 4 * 64 * 8 * 2;
  us* Wz3 = (us*)p;  p += 5 * 6 * 64 * 8 * 2;
  us* Wz4 = (us*)p;  p += 3 * 6 * 64 * 8 * 2;
  us* Wz5 = (us*)p;  p += 3 * 1 * 64 * 8 * 2;
  p = alignup(p, 256);
  float* bf1 = (float*)p; p += 96 * 4;
  float* bf2 = (float*)p; p += 64 * 4;
  float* bf3 = (float*)p; p += 96 * 4;
  float* bf4 = (float*)p; p += 96 * 4;
  float* bf5 = (float*)p; p += 16 * 4;
  float* co1 = (float*)p; p += 192 * 4;
  float* co2 = (float*)p; p += 128 * 4;
  float* co3 = (float*)p; p += 192 * 4;
  float* co4 = (float*)p; p += 192 * 4;
  float* co5 = (float*)p; p += 32 * 4;
  p = alignup(p, 256);
  float* partial = (float*)p; p += (size_t)GGEMM * 192 * 4;
  p = alignup(p, 256);
  char* zbase = p;
  int* counts = (int*)p;  p += (size_t)NN * 4;
  size_t zbytes = (size_t)(p - zbase);
  int* rowstart = (int*)p; p += (size_t)(NN + 1) * 4;
  int* bsum = (int*)p;    p += 256 * 4;
  us* rank = (us*)p;      p += (size_t)NE * 2;
  p = alignup(p, 4);
  unsigned* pack = (unsigned*)p; p += (size_t)NE * 4;

  hipMemsetAsync(zbase, 0, zbytes, stream);

  const int eb = (NE + 255) / 256;
  const int aggG = NN / 4;  // 12500, exact

  // ---- fused prep: f2bf | hist+rank | wprep1 | wprep2 ----
  prep_k<<<PB_WP2, 256, 0, stream>>>(x, xb, dst, counts, rank, c1_w, c1_b, Wz1,
                                     bf1, c2_w, c2_b, Wz2, bf2);
  scan_part<<<NB, 256, 0, stream>>>(counts, bsum);
  scan_apply<<<NB, 256, 0, stream>>>(counts, bsum, rowstart);
  scatter_k<<<eb, 256, 0, stream>>>(src, dst, ea, rowstart, rank, pack);

  // ---- conv1 ----
  agg_wave<<<aggG, 256, 0, stream>>>(xb, lin_w, lin_b, rowstart, pack, Ab);
  gemm_mfma<96, 0, 96, false><<<GGEMM, 256, 0, stream>>>(Ab, nullptr, Wz1, bf1,
                                                         H1, partial);
  bn_red<96><<<96, 256, 0, stream>>>(partial, c1_g, c1_be, co1);

  // ---- conv2 (BN1 coeff applied on the fly to H1) ----
  agg_wave_norm<<<aggG, 256, 0, stream>>>(H1, co1, lin_w, lin_b, rowstart,
                                          pack, Ab);
  gemm_mfma<96, 0, 64, false><<<GGEMM, 256, 0, stream>>>(Ab, nullptr, Wz2, bf2,
                                                         H2, partial);
  bn_red<64><<<64, 256, 0, stream>>>(partial, c2_g, c2_be, co2);

  // ---- lin1 on concat([H1(BN1 folded), H2(BN2 folded)]) ----
  wprep<160, 96, 96, 64><<<8, 256, 0, stream>>>(l1_w, l1_b, co1, co2, Wz3,
                                                bf3);
  gemm_mfma<96, 64, 96, false><<<GGEMM, 256, 0, stream>>>(H1, H2, Wz3, bf3, H3,
                                                          partial);
  bn_red<96><<<96, 256, 0, stream>>>(partial, l1_g, l1_be, co3);

  // ---- mlp1a (BN3 folded) ----
  wprep<96, 96, 96, 0><<<5, 256, 0, stream>>>(ma_w, ma_b, co3, nullptr, Wz4,
                                              bf4);
  gemm_mfma<96, 0, 96, false><<<GGEMM, 256, 0, stream>>>(H3, nullptr, Wz4, bf4,
                                                         H4, partial);
  bn_red<96><<<96, 256, 0, stream>>>(partial, ma_g, ma_be, co4);

  // ---- mlp1b (BN4 folded) -> H5 fp32, then BN5 via bn_red + bnout ----
  wprep<96, 16, 96, 0><<<1, 256, 0, stream>>>(mb_w, mb_b, co4, nullptr, Wz5,
                                              bf5);
  gemm_mfma<96, 0, 16, true><<<GGEMM, 256, 0, stream>>>(H4, nullptr, Wz5, bf5,
                                                        H5, partial);
  bn_red<16><<<16, 256, 0, stream>>>(partial, mb_g, mb_be, co5);
  bnout<<<(NN * 4 + 255) / 256, 256, 0, stream>>>((const float4*)H5, co5,
                                                  (float4*)d_out);
}